// Round 1
// baseline (851.388 us; speedup 1.0000x reference)
//
#include <hip/hip_runtime.h>

#define N_NODES 50000
#define N_EDGES 800000
#define IN_DIM 128
#define HID 128
#define OUT_DIM 64
#define BN_EPS 1e-5f

// ---------------------------------------------------------------------------
// CSR build: count -> scan -> fill
// ---------------------------------------------------------------------------
__global__ void count_edges(const int* __restrict__ ei, int* __restrict__ cnt) {
    int e = blockIdx.x * 256 + threadIdx.x;
    if (e < N_EDGES) {
        int d = ei[N_EDGES + e];   // dst
        atomicAdd(&cnt[d], 1);
    }
}

// single-block exclusive scan of cnt[0..N) -> row[0..N]; also cnt[i] := row[i]
// (cnt becomes the fill cursor)
__global__ __launch_bounds__(1024) void scan_rows(int* __restrict__ cnt, int* __restrict__ row) {
    __shared__ int part[1024];
    const int C = 49;                      // 1024*49 = 50176 >= N_NODES
    int t = threadIdx.x;
    int base = t * C;
    int s = 0;
    for (int j = 0; j < C; ++j) {
        int i = base + j;
        if (i < N_NODES) s += cnt[i];
    }
    part[t] = s;
    __syncthreads();
    int x = s;
    for (int off = 1; off < 1024; off <<= 1) {
        int y = (t >= off) ? part[t - off] : 0;
        __syncthreads();
        x += y;
        part[t] = x;
        __syncthreads();
    }
    int run = x - s;                       // exclusive prefix
    for (int j = 0; j < C; ++j) {
        int i = base + j;
        if (i < N_NODES) {
            int c = cnt[i];
            row[i] = run;
            cnt[i] = run;                  // cursor
            run += c;
        }
    }
    if (t == 1023) row[N_NODES] = run;     // == N_EDGES
}

__global__ void fill_csr(const int* __restrict__ ei, int* __restrict__ cursor,
                         int* __restrict__ csrc) {
    int e = blockIdx.x * 256 + threadIdx.x;
    if (e < N_EDGES) {
        int s = ei[e];                     // src
        int d = ei[N_EDGES + e];           // dst
        int p = atomicAdd(&cursor[d], 1);
        csrc[p] = s;
    }
}

// ---------------------------------------------------------------------------
// Mean aggregation: wave per node, lane holds float2 of the 128-dim row
// ---------------------------------------------------------------------------
__global__ __launch_bounds__(256) void agg_mean(const float* __restrict__ xin,
                                                const int* __restrict__ row,
                                                const int* __restrict__ csrc,
                                                float* __restrict__ mean) {
    int wave = threadIdx.x >> 6;
    int lane = threadIdx.x & 63;
    int node = blockIdx.x * 4 + wave;
    if (node >= N_NODES) return;
    int r0 = row[node], r1 = row[node + 1];
    const float2* xin2 = (const float2*)xin;
    float2 acc = {0.f, 0.f};
    for (int j = r0; j < r1; ++j) {
        int s = csrc[j];
        float2 v = xin2[(size_t)s * 64 + lane];
        acc.x += v.x;
        acc.y += v.y;
    }
    int deg = r1 - r0;
    float inv = 1.0f / (float)(deg > 1 ? deg : 1);
    acc.x *= inv;
    acc.y *= inv;
    ((float2*)mean)[(size_t)node * 64 + lane] = acc;
}

// ---------------------------------------------------------------------------
// Dual GEMM: out[n][o] = sum_k Wl[o][k]*mean[n][k] + sum_k Wr[o][k]*x[n][k] + b[o]
// Block = 256 threads (4 waves), 32 nodes/block, wave handles 8 nodes,
// lane computes O/64 outputs. Node rows staged in LDS (broadcast reads).
// ---------------------------------------------------------------------------
template <int O>
__global__ __launch_bounds__(256) void sage_gemm(const float* __restrict__ mean,
                                                 const float* __restrict__ xin,
                                                 const float* __restrict__ Wl,
                                                 const float* __restrict__ Wr,
                                                 const float* __restrict__ b,
                                                 float* __restrict__ out) {
    __shared__ float a_lds[32][256];       // [node][ mean(128) | x(128) ]
    int t = threadIdx.x;
    int nbase = blockIdx.x * 32;

    // stage 32 node rows (mean + x concatenated)
    for (int i = 0; i < 8; ++i) {
        int idx = i * 256 + t;
        int n = idx >> 6;                  // 0..31
        int c = idx & 63;                  // 0..63 float4 chunks
        int ng = nbase + n;
        float4 v = {0.f, 0.f, 0.f, 0.f};
        if (ng < N_NODES) {
            if (c < 32) v = ((const float4*)mean)[(size_t)ng * 32 + c];
            else        v = ((const float4*)xin)[(size_t)ng * 32 + (c - 32)];
        }
        *(float4*)&a_lds[n][c * 4] = v;
    }
    __syncthreads();

    int wv = t >> 6, l = t & 63;
    int n0 = wv * 8;
    constexpr int PO = O / 64;             // outputs per lane
    float acc[PO][8];
#pragma unroll
    for (int p = 0; p < PO; ++p)
#pragma unroll
        for (int n = 0; n < 8; ++n) acc[p][n] = 0.f;

    const float4* Wl4 = (const float4*)Wl;
    const float4* Wr4 = (const float4*)Wr;

#pragma unroll 2
    for (int k4 = 0; k4 < 32; ++k4) {
        float4 wl[PO], wr[PO];
#pragma unroll
        for (int p = 0; p < PO; ++p) {
            int o = l + p * 64;
            wl[p] = Wl4[o * 32 + k4];
            wr[p] = Wr4[o * 32 + k4];
        }
#pragma unroll
        for (int n = 0; n < 8; ++n) {
            float4 am = *(const float4*)&a_lds[n0 + n][k4 * 4];
            float4 ax = *(const float4*)&a_lds[n0 + n][128 + k4 * 4];
#pragma unroll
            for (int p = 0; p < PO; ++p) {
                acc[p][n] += wl[p].x * am.x + wl[p].y * am.y +
                             wl[p].z * am.z + wl[p].w * am.w +
                             wr[p].x * ax.x + wr[p].y * ax.y +
                             wr[p].z * ax.z + wr[p].w * ax.w;
            }
        }
    }

#pragma unroll
    for (int p = 0; p < PO; ++p) {
        int o = l + p * 64;
        float bias = b[o];
#pragma unroll
        for (int n = 0; n < 8; ++n) {
            int ng = nbase + n0 + n;
            if (ng < N_NODES) out[(size_t)ng * O + o] = acc[p][n] + bias;
        }
    }
}

// ---------------------------------------------------------------------------
// BN stats: column sum / sumsq over nodes
// ---------------------------------------------------------------------------
__global__ __launch_bounds__(256) void col_stats(const float* __restrict__ h,
                                                 float* __restrict__ cs,
                                                 float* __restrict__ cq) {
    int t = threadIdx.x;
    int f4 = t & 31;                       // float4 feature chunk
    int rg = t >> 5;                       // 0..7
    float4 s = {0, 0, 0, 0}, q = {0, 0, 0, 0};
    for (int n = blockIdx.x * 8 + rg; n < N_NODES; n += gridDim.x * 8) {
        float4 v = ((const float4*)h)[(size_t)n * 32 + f4];
        s.x += v.x; s.y += v.y; s.z += v.z; s.w += v.w;
        q.x += v.x * v.x; q.y += v.y * v.y; q.z += v.z * v.z; q.w += v.w * v.w;
    }
    __shared__ float4 sb[256], qb[256];
    sb[t] = s;
    qb[t] = q;
    __syncthreads();
    if (t < 32) {
        for (int g = 1; g < 8; ++g) {
            float4 s2 = sb[g * 32 + t], q2 = qb[g * 32 + t];
            s.x += s2.x; s.y += s2.y; s.z += s2.z; s.w += s2.w;
            q.x += q2.x; q.y += q2.y; q.z += q2.z; q.w += q2.w;
        }
        atomicAdd(&cs[t * 4 + 0], s.x);
        atomicAdd(&cs[t * 4 + 1], s.y);
        atomicAdd(&cs[t * 4 + 2], s.z);
        atomicAdd(&cs[t * 4 + 3], s.w);
        atomicAdd(&cq[t * 4 + 0], q.x);
        atomicAdd(&cq[t * 4 + 1], q.y);
        atomicAdd(&cq[t * 4 + 2], q.z);
        atomicAdd(&cq[t * 4 + 3], q.w);
    }
}

__global__ void bn_prep(const float* __restrict__ cs, const float* __restrict__ cq,
                        const float* __restrict__ g, const float* __restrict__ be,
                        float* __restrict__ scale, float* __restrict__ shift) {
    int f = threadIdx.x;                   // 128 threads
    float mu = cs[f] * (1.0f / N_NODES);
    float var = cq[f] * (1.0f / N_NODES) - mu * mu;
    float sc = g[f] * rsqrtf(var + BN_EPS);
    scale[f] = sc;
    shift[f] = be[f] - mu * sc;
}

__global__ __launch_bounds__(256) void bn_relu(float* __restrict__ h,
                                               const float* __restrict__ scale,
                                               const float* __restrict__ shift) {
    int idx = blockIdx.x * 256 + threadIdx.x;   // float4 index
    if (idx >= N_NODES * 32) return;
    int f0 = (idx & 31) * 4;
    float4 v = ((float4*)h)[idx];
    v.x = fmaxf(v.x * scale[f0 + 0] + shift[f0 + 0], 0.f);
    v.y = fmaxf(v.y * scale[f0 + 1] + shift[f0 + 1], 0.f);
    v.z = fmaxf(v.z * scale[f0 + 2] + shift[f0 + 2], 0.f);
    v.w = fmaxf(v.w * scale[f0 + 3] + shift[f0 + 3], 0.f);
    ((float4*)h)[idx] = v;
}

// ---------------------------------------------------------------------------
extern "C" void kernel_launch(void* const* d_in, const int* in_sizes, int n_in,
                              void* d_out, int out_size, void* d_ws, size_t ws_size,
                              hipStream_t stream) {
    const float* x   = (const float*)d_in[0];
    const int*   ei  = (const int*)d_in[1];
    const float* Wl1 = (const float*)d_in[2];
    const float* Wr1 = (const float*)d_in[3];
    const float* b1  = (const float*)d_in[4];
    const float* g1  = (const float*)d_in[5];
    const float* be1 = (const float*)d_in[6];
    const float* Wl2 = (const float*)d_in[7];
    const float* Wr2 = (const float*)d_in[8];
    const float* b2  = (const float*)d_in[9];
    const float* g2  = (const float*)d_in[10];
    const float* be2 = (const float*)d_in[11];
    const float* Wl3 = (const float*)d_in[12];
    const float* Wr3 = (const float*)d_in[13];
    const float* b3  = (const float*)d_in[14];
    float* out = (float*)d_out;

    // workspace layout (256B aligned)
    char* p = (char*)d_ws;
    size_t off = 0;
    auto alloc = [&](size_t bytes) {
        char* r = p + off;
        off = (off + bytes + 255) & ~(size_t)255;
        return r;
    };
    int*   cnt  = (int*)alloc((size_t)N_NODES * 4);          // counts -> cursor
    int*   row  = (int*)alloc((size_t)(N_NODES + 1) * 4);
    int*   csrc = (int*)alloc((size_t)N_EDGES * 4);
    float* mn   = (float*)alloc((size_t)N_NODES * 128 * 4);
    float* h1   = (float*)alloc((size_t)N_NODES * 128 * 4);
    float* h2   = (float*)alloc((size_t)N_NODES * 128 * 4);
    float* cs   = (float*)alloc(128 * 4);
    float* cq   = (float*)alloc(128 * 4);
    float* scl  = (float*)alloc(128 * 4);
    float* shf  = (float*)alloc(128 * 4);
    (void)ws_size; (void)n_in; (void)in_sizes; (void)out_size;

    const int EBLK = (N_EDGES + 255) / 256;          // 3125
    const int NBLK4 = (N_NODES + 3) / 4;             // 12500
    const int GBLK = (N_NODES + 31) / 32;            // 1563
    const int BNBLK = (N_NODES * 32 + 255) / 256;    // 6250

    // CSR build
    hipMemsetAsync(cnt, 0, (size_t)N_NODES * 4, stream);
    count_edges<<<EBLK, 256, 0, stream>>>(ei, cnt);
    scan_rows<<<1, 1024, 0, stream>>>(cnt, row);
    fill_csr<<<EBLK, 256, 0, stream>>>(ei, cnt, csrc);

    // Layer 1
    agg_mean<<<NBLK4, 256, 0, stream>>>(x, row, csrc, mn);
    sage_gemm<128><<<GBLK, 256, 0, stream>>>(mn, x, Wl1, Wr1, b1, h1);
    hipMemsetAsync(cs, 0, 2 * 128 * 4, stream);      // cs,cq contiguous-ish? separate:
    hipMemsetAsync(cq, 0, 128 * 4, stream);
    col_stats<<<256, 256, 0, stream>>>(h1, cs, cq);
    bn_prep<<<1, 128, 0, stream>>>(cs, cq, g1, be1, scl, shf);
    bn_relu<<<BNBLK, 256, 0, stream>>>(h1, scl, shf);

    // Layer 2
    agg_mean<<<NBLK4, 256, 0, stream>>>(h1, row, csrc, mn);
    sage_gemm<128><<<GBLK, 256, 0, stream>>>(mn, h1, Wl2, Wr2, b2, h2);
    hipMemsetAsync(cs, 0, 128 * 4, stream);
    hipMemsetAsync(cq, 0, 128 * 4, stream);
    col_stats<<<256, 256, 0, stream>>>(h2, cs, cq);
    bn_prep<<<1, 128, 0, stream>>>(cs, cq, g2, be2, scl, shf);
    bn_relu<<<BNBLK, 256, 0, stream>>>(h2, scl, shf);

    // Layer 3 (no BN/ReLU), O = 64, straight to d_out
    agg_mean<<<NBLK4, 256, 0, stream>>>(h2, row, csrc, mn);
    sage_gemm<64><<<GBLK, 256, 0, stream>>>(mn, h2, Wl3, Wr3, b3, out);
}

// Round 2
// 554.617 us; speedup vs baseline: 1.5351x; 1.5351x over previous
//
#include <hip/hip_runtime.h>

#define N_NODES 50000
#define N_EDGES 800000
#define BN_EPS 1e-5f

typedef __bf16 bf16x8 __attribute__((ext_vector_type(8)));
typedef float f32x4 __attribute__((ext_vector_type(4)));

static __device__ __forceinline__ unsigned short f2b(float f) {
    unsigned int u = __float_as_uint(f);
    return (unsigned short)((u + 0x7FFFu + ((u >> 16) & 1u)) >> 16);   // RNE
}
static __device__ __forceinline__ float bl(unsigned int u) { return __uint_as_float(u << 16); }
static __device__ __forceinline__ float bh(unsigned int u) { return __uint_as_float(u & 0xFFFF0000u); }

// ---------------------------------------------------------------------------
// CSR build: count -> scan -> fill
// ---------------------------------------------------------------------------
__global__ void count_edges(const int* __restrict__ ei, int* __restrict__ cnt) {
    int e = blockIdx.x * 256 + threadIdx.x;
    if (e < N_EDGES) atomicAdd(&cnt[ei[N_EDGES + e]], 1);
}

__global__ __launch_bounds__(1024) void scan_rows(int* __restrict__ cnt, int* __restrict__ row) {
    __shared__ int part[1024];
    const int C = 49;
    int t = threadIdx.x;
    int base = t * C;
    int s = 0;
    for (int j = 0; j < C; ++j) {
        int i = base + j;
        if (i < N_NODES) s += cnt[i];
    }
    part[t] = s;
    __syncthreads();
    int x = s;
    for (int off = 1; off < 1024; off <<= 1) {
        int y = (t >= off) ? part[t - off] : 0;
        __syncthreads();
        x += y;
        part[t] = x;
        __syncthreads();
    }
    int run = x - s;
    for (int j = 0; j < C; ++j) {
        int i = base + j;
        if (i < N_NODES) {
            int c = cnt[i];
            row[i] = run;
            cnt[i] = run;
            run += c;
        }
    }
    if (t == 1023) row[N_NODES] = run;
}

__global__ void fill_csr(const int* __restrict__ ei, int* __restrict__ cursor,
                         int* __restrict__ csrc) {
    int e = blockIdx.x * 256 + threadIdx.x;
    if (e < N_EDGES) {
        int s = ei[e];
        int d = ei[N_EDGES + e];
        int p = atomicAdd(&cursor[d], 1);
        csrc[p] = s;
    }
}

// ---------------------------------------------------------------------------
// Casts
// ---------------------------------------------------------------------------
__global__ __launch_bounds__(256) void cast_x(const float* __restrict__ in,
                                              unsigned short* __restrict__ out) {
    int idx = blockIdx.x * 256 + threadIdx.x;          // float4 chunk
    if (idx >= N_NODES * 32) return;
    float4 v = ((const float4*)in)[idx];
    uint2 p;
    p.x = (unsigned int)f2b(v.x) | ((unsigned int)f2b(v.y) << 16);
    p.y = (unsigned int)f2b(v.z) | ((unsigned int)f2b(v.w) << 16);
    ((uint2*)out)[idx] = p;
}

__global__ void wcast(const float* __restrict__ Wl1, const float* __restrict__ Wr1,
                      const float* __restrict__ Wl2, const float* __restrict__ Wr2,
                      const float* __restrict__ Wl3, const float* __restrict__ Wr3,
                      unsigned short* __restrict__ out) {
    int idx = blockIdx.x * 256 + threadIdx.x;
    if (idx >= 81920) return;
    float v;
    if (idx < 16384)       v = Wl1[idx];
    else if (idx < 32768)  v = Wr1[idx - 16384];
    else if (idx < 49152)  v = Wl2[idx - 32768];
    else if (idx < 65536)  v = Wr2[idx - 49152];
    else if (idx < 73728)  v = Wl3[idx - 65536];
    else                   v = Wr3[idx - 73728];
    out[idx] = f2b(v);
}

// ---------------------------------------------------------------------------
// Mean aggregation (bf16 rows): wave per node, lane holds 2 bf16 (uint)
// ---------------------------------------------------------------------------
__global__ __launch_bounds__(256) void agg_mean_bf16(const unsigned short* __restrict__ xin,
                                                     const int* __restrict__ row,
                                                     const int* __restrict__ csrc,
                                                     unsigned short* __restrict__ mean) {
    int wave = threadIdx.x >> 6;
    int lane = threadIdx.x & 63;
    int node = blockIdx.x * 4 + wave;
    if (node >= N_NODES) return;
    int r0 = row[node], r1 = row[node + 1];
    const unsigned int* xin1 = (const unsigned int*)xin;   // row stride 64 uints
    float ax = 0.f, ay = 0.f;
    int j = r0;
    for (; j + 1 < r1; j += 2) {
        int s0 = csrc[j];
        int s1 = csrc[j + 1];
        unsigned int v0 = xin1[(size_t)s0 * 64 + lane];
        unsigned int v1 = xin1[(size_t)s1 * 64 + lane];
        ax += bl(v0) + bl(v1);
        ay += bh(v0) + bh(v1);
    }
    if (j < r1) {
        unsigned int v = xin1[(size_t)csrc[j] * 64 + lane];
        ax += bl(v);
        ay += bh(v);
    }
    int deg = r1 - r0;
    float inv = 1.0f / (float)(deg > 1 ? deg : 1);
    unsigned int p = (unsigned int)f2b(ax * inv) | ((unsigned int)f2b(ay * inv) << 16);
    ((unsigned int*)mean)[(size_t)node * 64 + lane] = p;
}

// ---------------------------------------------------------------------------
// MFMA dual-GEMM: out[n][o] = mean[n]·Wl[o] + x[n]·Wr[o] + b[o]
// block = 256 thr (4 waves), 64 rows/block, wave owns 16 rows × O cols.
// All fragments loaded straight from row-major bf16 global memory.
// ---------------------------------------------------------------------------
template <int O, bool BF16OUT>
__global__ __launch_bounds__(256) void gemm_mfma(const unsigned short* __restrict__ Am,
                                                 const unsigned short* __restrict__ Ax,
                                                 const unsigned short* __restrict__ Wl,
                                                 const unsigned short* __restrict__ Wr,
                                                 const float* __restrict__ bias,
                                                 unsigned short* __restrict__ hout,
                                                 float* __restrict__ fout) {
    constexpr int NF = O / 16;
    int t = threadIdx.x;
    int wv = t >> 6, l = t & 63;
    int lr = l & 15;                     // A-row within 16-tile / B-col within frag
    int ko = l >> 4;                     // k-chunk (elements ko*8 .. +8)
    int arow = blockIdx.x * 64 + wv * 16 + lr;
    int ar = arow < N_NODES ? arow : N_NODES - 1;
    const bf16x8* am = (const bf16x8*)(Am + (size_t)ar * 128);
    const bf16x8* ax = (const bf16x8*)(Ax + (size_t)ar * 128);

    f32x4 acc[NF];
#pragma unroll
    for (int nf = 0; nf < NF; ++nf) acc[nf] = (f32x4){0.f, 0.f, 0.f, 0.f};

#pragma unroll
    for (int ks = 0; ks < 4; ++ks) {
        bf16x8 a1 = am[ks * 4 + ko];
        bf16x8 a2 = ax[ks * 4 + ko];
#pragma unroll
        for (int nf = 0; nf < NF; ++nf) {
            const bf16x8* wlp = (const bf16x8*)(Wl + (size_t)(nf * 16 + lr) * 128);
            const bf16x8* wrp = (const bf16x8*)(Wr + (size_t)(nf * 16 + lr) * 128);
            acc[nf] = __builtin_amdgcn_mfma_f32_16x16x32_bf16(a1, wlp[ks * 4 + ko], acc[nf], 0, 0, 0);
            acc[nf] = __builtin_amdgcn_mfma_f32_16x16x32_bf16(a2, wrp[ks * 4 + ko], acc[nf], 0, 0, 0);
        }
    }

    // C/D layout: col = lane&15, row = (lane>>4)*4 + reg
    int orow0 = blockIdx.x * 64 + wv * 16 + ko * 4;
#pragma unroll
    for (int nf = 0; nf < NF; ++nf) {
        int col = nf * 16 + lr;
        float bs = bias[col];
#pragma unroll
        for (int j = 0; j < 4; ++j) {
            int r = orow0 + j;
            if (r < N_NODES) {
                float v = acc[nf][j] + bs;
                if (BF16OUT) hout[(size_t)r * 128 + col] = f2b(v);
                else         fout[(size_t)r * 64 + col] = v;
            }
        }
    }
}

// ---------------------------------------------------------------------------
// BN stats over bf16 h
// ---------------------------------------------------------------------------
__global__ __launch_bounds__(256) void col_stats_bf16(const unsigned short* __restrict__ h,
                                                      float* __restrict__ cs,
                                                      float* __restrict__ cq) {
    int t = threadIdx.x;
    int f4 = t & 31;                       // 4-feature chunk
    int rg = t >> 5;
    float s0 = 0, s1 = 0, s2 = 0, s3 = 0, q0 = 0, q1 = 0, q2 = 0, q3 = 0;
    for (int n = blockIdx.x * 8 + rg; n < N_NODES; n += gridDim.x * 8) {
        uint2 v = ((const uint2*)h)[(size_t)n * 32 + f4];
        float a = bl(v.x), b = bh(v.x), c = bl(v.y), d = bh(v.y);
        s0 += a; s1 += b; s2 += c; s3 += d;
        q0 += a * a; q1 += b * b; q2 += c * c; q3 += d * d;
    }
    __shared__ float4 sb[256], qb[256];
    sb[t] = make_float4(s0, s1, s2, s3);
    qb[t] = make_float4(q0, q1, q2, q3);
    __syncthreads();
    if (t < 32) {
        float4 S = sb[t], Q = qb[t];
        for (int g = 1; g < 8; ++g) {
            float4 s2v = sb[g * 32 + t], q2v = qb[g * 32 + t];
            S.x += s2v.x; S.y += s2v.y; S.z += s2v.z; S.w += s2v.w;
            Q.x += q2v.x; Q.y += q2v.y; Q.z += q2v.z; Q.w += q2v.w;
        }
        atomicAdd(&cs[t * 4 + 0], S.x);
        atomicAdd(&cs[t * 4 + 1], S.y);
        atomicAdd(&cs[t * 4 + 2], S.z);
        atomicAdd(&cs[t * 4 + 3], S.w);
        atomicAdd(&cq[t * 4 + 0], Q.x);
        atomicAdd(&cq[t * 4 + 1], Q.y);
        atomicAdd(&cq[t * 4 + 2], Q.z);
        atomicAdd(&cq[t * 4 + 3], Q.w);
    }
}

__global__ void bn_prep(const float* __restrict__ cs, const float* __restrict__ cq,
                        const float* __restrict__ g, const float* __restrict__ be,
                        float* __restrict__ scale, float* __restrict__ shift) {
    int f = threadIdx.x;
    float mu = cs[f] * (1.0f / N_NODES);
    float var = cq[f] * (1.0f / N_NODES) - mu * mu;
    float sc = g[f] * rsqrtf(var + BN_EPS);
    scale[f] = sc;
    shift[f] = be[f] - mu * sc;
}

__global__ __launch_bounds__(256) void bn_relu_bf16(unsigned short* __restrict__ h,
                                                    const float* __restrict__ scale,
                                                    const float* __restrict__ shift) {
    int idx = blockIdx.x * 256 + threadIdx.x;   // 4-feature chunk
    if (idx >= N_NODES * 32) return;
    int f0 = (idx & 31) * 4;
    uint2 v = ((uint2*)h)[idx];
    float a = fmaxf(bl(v.x) * scale[f0 + 0] + shift[f0 + 0], 0.f);
    float b = fmaxf(bh(v.x) * scale[f0 + 1] + shift[f0 + 1], 0.f);
    float c = fmaxf(bl(v.y) * scale[f0 + 2] + shift[f0 + 2], 0.f);
    float d = fmaxf(bh(v.y) * scale[f0 + 3] + shift[f0 + 3], 0.f);
    uint2 p;
    p.x = (unsigned int)f2b(a) | ((unsigned int)f2b(b) << 16);
    p.y = (unsigned int)f2b(c) | ((unsigned int)f2b(d) << 16);
    ((uint2*)h)[idx] = p;
}

// ---------------------------------------------------------------------------
extern "C" void kernel_launch(void* const* d_in, const int* in_sizes, int n_in,
                              void* d_out, int out_size, void* d_ws, size_t ws_size,
                              hipStream_t stream) {
    const float* x   = (const float*)d_in[0];
    const int*   ei  = (const int*)d_in[1];
    const float* Wl1 = (const float*)d_in[2];
    const float* Wr1 = (const float*)d_in[3];
    const float* b1  = (const float*)d_in[4];
    const float* g1  = (const float*)d_in[5];
    const float* be1 = (const float*)d_in[6];
    const float* Wl2 = (const float*)d_in[7];
    const float* Wr2 = (const float*)d_in[8];
    const float* b2  = (const float*)d_in[9];
    const float* g2  = (const float*)d_in[10];
    const float* be2 = (const float*)d_in[11];
    const float* Wl3 = (const float*)d_in[12];
    const float* Wr3 = (const float*)d_in[13];
    const float* b3  = (const float*)d_in[14];
    float* out = (float*)d_out;

    char* p = (char*)d_ws;
    size_t off = 0;
    auto alloc = [&](size_t bytes) {
        char* r = p + off;
        off = (off + bytes + 255) & ~(size_t)255;
        return r;
    };
    int*            cnt  = (int*)alloc((size_t)N_NODES * 4);
    int*            row  = (int*)alloc((size_t)(N_NODES + 1) * 4);
    int*            csrc = (int*)alloc((size_t)N_EDGES * 4);
    unsigned short* xb   = (unsigned short*)alloc((size_t)N_NODES * 128 * 2);
    unsigned short* mn   = (unsigned short*)alloc((size_t)N_NODES * 128 * 2);
    unsigned short* h1   = (unsigned short*)alloc((size_t)N_NODES * 128 * 2);
    unsigned short* h2   = (unsigned short*)alloc((size_t)N_NODES * 128 * 2);
    unsigned short* wbf  = (unsigned short*)alloc((size_t)81920 * 2);
    float*          cs   = (float*)alloc(128 * 4);
    float*          cq   = (float*)alloc(128 * 4);
    float*          scl  = (float*)alloc(128 * 4);
    float*          shf  = (float*)alloc(128 * 4);
    (void)ws_size; (void)n_in; (void)in_sizes; (void)out_size;

    unsigned short* wl1b = wbf;
    unsigned short* wr1b = wbf + 16384;
    unsigned short* wl2b = wbf + 32768;
    unsigned short* wr2b = wbf + 49152;
    unsigned short* wl3b = wbf + 65536;
    unsigned short* wr3b = wbf + 73728;

    const int EBLK  = (N_EDGES + 255) / 256;       // 3125
    const int NBLK4 = (N_NODES + 3) / 4;           // 12500
    const int GBLK  = (N_NODES + 63) / 64;         // 782
    const int CBLK  = (N_NODES * 32 + 255) / 256;  // 6250

    // casts + CSR build
    cast_x<<<CBLK, 256, 0, stream>>>(x, xb);
    wcast<<<320, 256, 0, stream>>>(Wl1, Wr1, Wl2, Wr2, Wl3, Wr3, wbf);
    hipMemsetAsync(cnt, 0, (size_t)N_NODES * 4, stream);
    count_edges<<<EBLK, 256, 0, stream>>>(ei, cnt);
    scan_rows<<<1, 1024, 0, stream>>>(cnt, row);
    fill_csr<<<EBLK, 256, 0, stream>>>(ei, cnt, csrc);

    // Layer 1
    agg_mean_bf16<<<NBLK4, 256, 0, stream>>>(xb, row, csrc, mn);
    gemm_mfma<128, true><<<GBLK, 256, 0, stream>>>(mn, xb, wl1b, wr1b, b1, h1, nullptr);
    hipMemsetAsync(cs, 0, 128 * 4, stream);
    hipMemsetAsync(cq, 0, 128 * 4, stream);
    col_stats_bf16<<<256, 256, 0, stream>>>(h1, cs, cq);
    bn_prep<<<1, 128, 0, stream>>>(cs, cq, g1, be1, scl, shf);
    bn_relu_bf16<<<CBLK, 256, 0, stream>>>(h1, scl, shf);

    // Layer 2
    agg_mean_bf16<<<NBLK4, 256, 0, stream>>>(h1, row, csrc, mn);
    gemm_mfma<128, true><<<GBLK, 256, 0, stream>>>(mn, h1, wl2b, wr2b, b2, h2, nullptr);
    hipMemsetAsync(cs, 0, 128 * 4, stream);
    hipMemsetAsync(cq, 0, 128 * 4, stream);
    col_stats_bf16<<<256, 256, 0, stream>>>(h2, cs, cq);
    bn_prep<<<1, 128, 0, stream>>>(cs, cq, g2, be2, scl, shf);
    bn_relu_bf16<<<CBLK, 256, 0, stream>>>(h2, scl, shf);

    // Layer 3 -> f32 d_out
    agg_mean_bf16<<<NBLK4, 256, 0, stream>>>(h2, row, csrc, mn);
    gemm_mfma<64, false><<<GBLK, 256, 0, stream>>>(mn, h2, wl3b, wr3b, b3, nullptr, out);
}

// Round 3
// 441.930 us; speedup vs baseline: 1.9265x; 1.2550x over previous
//
#include <hip/hip_runtime.h>

#define N_NODES 50000
#define N_EDGES 800000
#define BN_EPS 1e-5f
#define SCAN_BLOCKS 196   // ceil(50000/256)

typedef __bf16 bf16x8 __attribute__((ext_vector_type(8)));
typedef float f32x4 __attribute__((ext_vector_type(4)));

static __device__ __forceinline__ unsigned short f2b(float f) {
    unsigned int u = __float_as_uint(f);
    return (unsigned short)((u + 0x7FFFu + ((u >> 16) & 1u)) >> 16);   // RNE
}
static __device__ __forceinline__ float bl(unsigned int u) { return __uint_as_float(u << 16); }
static __device__ __forceinline__ float bh(unsigned int u) { return __uint_as_float(u & 0xFFFF0000u); }

// ---------------------------------------------------------------------------
// CSR build: count -> 2-level scan -> fill
// ---------------------------------------------------------------------------
__global__ void count_edges(const int* __restrict__ ei, int* __restrict__ cnt) {
    int e = blockIdx.x * 256 + threadIdx.x;
    if (e < N_EDGES) atomicAdd(&cnt[ei[N_EDGES + e]], 1);
}

__global__ __launch_bounds__(256) void partial_sums(const int* __restrict__ cnt,
                                                    int* __restrict__ partials) {
    int t = threadIdx.x;
    int i = blockIdx.x * 256 + t;
    int v = (i < N_NODES) ? cnt[i] : 0;
    __shared__ int sm[256];
    sm[t] = v;
    __syncthreads();
    for (int off = 128; off > 0; off >>= 1) {
        if (t < off) sm[t] += sm[t + off];
        __syncthreads();
    }
    if (t == 0) partials[blockIdx.x] = sm[0];
}

__global__ __launch_bounds__(256) void scan_partials(int* __restrict__ partials,
                                                     int* __restrict__ row) {
    __shared__ int sm[256];
    int t = threadIdx.x;
    int v = (t < SCAN_BLOCKS) ? partials[t] : 0;
    sm[t] = v;
    __syncthreads();
    int x = v;
    for (int off = 1; off < 256; off <<= 1) {
        int y = (t >= off) ? sm[t - off] : 0;
        __syncthreads();
        x += y;
        sm[t] = x;
        __syncthreads();
    }
    if (t < SCAN_BLOCKS) partials[t] = x - v;   // exclusive
    if (t == 0) row[N_NODES] = N_EDGES;
}

__global__ __launch_bounds__(256) void scan_apply(const int* __restrict__ cnt,
                                                  const int* __restrict__ partials,
                                                  int* __restrict__ row,
                                                  int* __restrict__ cursor) {
    int t = threadIdx.x;
    int i = blockIdx.x * 256 + t;
    int v = (i < N_NODES) ? cnt[i] : 0;
    __shared__ int sm[256];
    sm[t] = v;
    __syncthreads();
    int x = v;
    for (int off = 1; off < 256; off <<= 1) {
        int y = (t >= off) ? sm[t - off] : 0;
        __syncthreads();
        x += y;
        sm[t] = x;
        __syncthreads();
    }
    int pre = x - v + partials[blockIdx.x];
    if (i < N_NODES) {
        row[i] = pre;
        cursor[i] = pre;
    }
}

__global__ void fill_csr(const int* __restrict__ ei, int* __restrict__ cursor,
                         int* __restrict__ csrc) {
    int e = blockIdx.x * 256 + threadIdx.x;
    if (e < N_EDGES) {
        int s = ei[e];
        int d = ei[N_EDGES + e];
        int p = atomicAdd(&cursor[d], 1);
        csrc[p] = s;
    }
}

// ---------------------------------------------------------------------------
// Casts
// ---------------------------------------------------------------------------
__global__ __launch_bounds__(256) void cast_x(const float* __restrict__ in,
                                              unsigned short* __restrict__ out) {
    int idx = blockIdx.x * 256 + threadIdx.x;          // float4 chunk
    if (idx >= N_NODES * 32) return;
    float4 v = ((const float4*)in)[idx];
    uint2 p;
    p.x = (unsigned int)f2b(v.x) | ((unsigned int)f2b(v.y) << 16);
    p.y = (unsigned int)f2b(v.z) | ((unsigned int)f2b(v.w) << 16);
    ((uint2*)out)[idx] = p;
}

__global__ void wcast(const float* __restrict__ Wl1, const float* __restrict__ Wr1,
                      const float* __restrict__ Wl2, const float* __restrict__ Wr2,
                      const float* __restrict__ Wl3, const float* __restrict__ Wr3,
                      unsigned short* __restrict__ out) {
    int idx = blockIdx.x * 256 + threadIdx.x;
    if (idx >= 81920) return;
    float v;
    if (idx < 16384)       v = Wl1[idx];
    else if (idx < 32768)  v = Wr1[idx - 16384];
    else if (idx < 49152)  v = Wl2[idx - 32768];
    else if (idx < 65536)  v = Wr2[idx - 49152];
    else if (idx < 73728)  v = Wl3[idx - 65536];
    else                   v = Wr3[idx - 73728];
    out[idx] = f2b(v);
}

// ---------------------------------------------------------------------------
// Mean aggregation (bf16 rows): wave per node, lane holds 2 bf16 (uint)
// ---------------------------------------------------------------------------
__global__ __launch_bounds__(256) void agg_mean_bf16(const unsigned short* __restrict__ xin,
                                                     const int* __restrict__ row,
                                                     const int* __restrict__ csrc,
                                                     unsigned short* __restrict__ mean) {
    int wave = threadIdx.x >> 6;
    int lane = threadIdx.x & 63;
    int node = blockIdx.x * 4 + wave;
    if (node >= N_NODES) return;
    int r0 = row[node], r1 = row[node + 1];
    const unsigned int* xin1 = (const unsigned int*)xin;   // row stride 64 uints
    float ax = 0.f, ay = 0.f;
    int j = r0;
    for (; j + 1 < r1; j += 2) {
        int s0 = csrc[j];
        int s1 = csrc[j + 1];
        unsigned int v0 = xin1[(size_t)s0 * 64 + lane];
        unsigned int v1 = xin1[(size_t)s1 * 64 + lane];
        ax += bl(v0) + bl(v1);
        ay += bh(v0) + bh(v1);
    }
    if (j < r1) {
        unsigned int v = xin1[(size_t)csrc[j] * 64 + lane];
        ax += bl(v);
        ay += bh(v);
    }
    int deg = r1 - r0;
    float inv = 1.0f / (float)(deg > 1 ? deg : 1);
    unsigned int p = (unsigned int)f2b(ax * inv) | ((unsigned int)f2b(ay * inv) << 16);
    ((unsigned int*)mean)[(size_t)node * 64 + lane] = p;
}

// ---------------------------------------------------------------------------
// MFMA dual-GEMM: out[n][o] = mean[n]·Wl[o] + x[n]·Wr[o] + b[o]
// block = 256 thr (4 waves), 64 rows/block, wave owns 16 rows × O cols.
// All fragments loaded straight from row-major bf16 global memory.
// ---------------------------------------------------------------------------
template <int O, bool BF16OUT>
__global__ __launch_bounds__(256) void gemm_mfma(const unsigned short* __restrict__ Am,
                                                 const unsigned short* __restrict__ Ax,
                                                 const unsigned short* __restrict__ Wl,
                                                 const unsigned short* __restrict__ Wr,
                                                 const float* __restrict__ bias,
                                                 unsigned short* __restrict__ hout,
                                                 float* __restrict__ fout) {
    constexpr int NF = O / 16;
    int t = threadIdx.x;
    int wv = t >> 6, l = t & 63;
    int lr = l & 15;                     // A-row within 16-tile / B-col within frag
    int ko = l >> 4;                     // k-chunk (elements ko*8 .. +8)
    int arow = blockIdx.x * 64 + wv * 16 + lr;
    int ar = arow < N_NODES ? arow : N_NODES - 1;
    const bf16x8* am = (const bf16x8*)(Am + (size_t)ar * 128);
    const bf16x8* ax = (const bf16x8*)(Ax + (size_t)ar * 128);

    f32x4 acc[NF];
#pragma unroll
    for (int nf = 0; nf < NF; ++nf) acc[nf] = (f32x4){0.f, 0.f, 0.f, 0.f};

#pragma unroll
    for (int ks = 0; ks < 4; ++ks) {
        bf16x8 a1 = am[ks * 4 + ko];
        bf16x8 a2 = ax[ks * 4 + ko];
#pragma unroll
        for (int nf = 0; nf < NF; ++nf) {
            const bf16x8* wlp = (const bf16x8*)(Wl + (size_t)(nf * 16 + lr) * 128);
            const bf16x8* wrp = (const bf16x8*)(Wr + (size_t)(nf * 16 + lr) * 128);
            acc[nf] = __builtin_amdgcn_mfma_f32_16x16x32_bf16(a1, wlp[ks * 4 + ko], acc[nf], 0, 0, 0);
            acc[nf] = __builtin_amdgcn_mfma_f32_16x16x32_bf16(a2, wrp[ks * 4 + ko], acc[nf], 0, 0, 0);
        }
    }

    // C/D layout: col = lane&15, row = (lane>>4)*4 + reg
    int orow0 = blockIdx.x * 64 + wv * 16 + ko * 4;
#pragma unroll
    for (int nf = 0; nf < NF; ++nf) {
        int col = nf * 16 + lr;
        float bs = bias[col];
#pragma unroll
        for (int j = 0; j < 4; ++j) {
            int r = orow0 + j;
            if (r < N_NODES) {
                float v = acc[nf][j] + bs;
                if (BF16OUT) hout[(size_t)r * 128 + col] = f2b(v);
                else         fout[(size_t)r * 64 + col] = v;
            }
        }
    }
}

// ---------------------------------------------------------------------------
// BN stats over bf16 h
// ---------------------------------------------------------------------------
__global__ __launch_bounds__(256) void col_stats_bf16(const unsigned short* __restrict__ h,
                                                      float* __restrict__ cs,
                                                      float* __restrict__ cq) {
    int t = threadIdx.x;
    int f4 = t & 31;                       // 4-feature chunk
    int rg = t >> 5;
    float s0 = 0, s1 = 0, s2 = 0, s3 = 0, q0 = 0, q1 = 0, q2 = 0, q3 = 0;
    for (int n = blockIdx.x * 8 + rg; n < N_NODES; n += gridDim.x * 8) {
        uint2 v = ((const uint2*)h)[(size_t)n * 32 + f4];
        float a = bl(v.x), b = bh(v.x), c = bl(v.y), d = bh(v.y);
        s0 += a; s1 += b; s2 += c; s3 += d;
        q0 += a * a; q1 += b * b; q2 += c * c; q3 += d * d;
    }
    __shared__ float4 sb[256], qb[256];
    sb[t] = make_float4(s0, s1, s2, s3);
    qb[t] = make_float4(q0, q1, q2, q3);
    __syncthreads();
    if (t < 32) {
        float4 S = sb[t], Q = qb[t];
        for (int g = 1; g < 8; ++g) {
            float4 s2v = sb[g * 32 + t], q2v = qb[g * 32 + t];
            S.x += s2v.x; S.y += s2v.y; S.z += s2v.z; S.w += s2v.w;
            Q.x += q2v.x; Q.y += q2v.y; Q.z += q2v.z; Q.w += q2v.w;
        }
        atomicAdd(&cs[t * 4 + 0], S.x);
        atomicAdd(&cs[t * 4 + 1], S.y);
        atomicAdd(&cs[t * 4 + 2], S.z);
        atomicAdd(&cs[t * 4 + 3], S.w);
        atomicAdd(&cq[t * 4 + 0], Q.x);
        atomicAdd(&cq[t * 4 + 1], Q.y);
        atomicAdd(&cq[t * 4 + 2], Q.z);
        atomicAdd(&cq[t * 4 + 3], Q.w);
    }
}

__global__ void bn_prep(const float* __restrict__ cs, const float* __restrict__ cq,
                        const float* __restrict__ g, const float* __restrict__ be,
                        float* __restrict__ scale, float* __restrict__ shift) {
    int f = threadIdx.x;
    float mu = cs[f] * (1.0f / N_NODES);
    float var = cq[f] * (1.0f / N_NODES) - mu * mu;
    float sc = g[f] * rsqrtf(var + BN_EPS);
    scale[f] = sc;
    shift[f] = be[f] - mu * sc;
}

__global__ __launch_bounds__(256) void bn_relu_bf16(unsigned short* __restrict__ h,
                                                    const float* __restrict__ scale,
                                                    const float* __restrict__ shift) {
    int idx = blockIdx.x * 256 + threadIdx.x;   // 4-feature chunk
    if (idx >= N_NODES * 32) return;
    int f0 = (idx & 31) * 4;
    uint2 v = ((uint2*)h)[idx];
    float a = fmaxf(bl(v.x) * scale[f0 + 0] + shift[f0 + 0], 0.f);
    float b = fmaxf(bh(v.x) * scale[f0 + 1] + shift[f0 + 1], 0.f);
    float c = fmaxf(bl(v.y) * scale[f0 + 2] + shift[f0 + 2], 0.f);
    float d = fmaxf(bh(v.y) * scale[f0 + 3] + shift[f0 + 3], 0.f);
    uint2 p;
    p.x = (unsigned int)f2b(a) | ((unsigned int)f2b(b) << 16);
    p.y = (unsigned int)f2b(c) | ((unsigned int)f2b(d) << 16);
    ((uint2*)h)[idx] = p;
}

// ---------------------------------------------------------------------------
extern "C" void kernel_launch(void* const* d_in, const int* in_sizes, int n_in,
                              void* d_out, int out_size, void* d_ws, size_t ws_size,
                              hipStream_t stream) {
    const float* x   = (const float*)d_in[0];
    const int*   ei  = (const int*)d_in[1];
    const float* Wl1 = (const float*)d_in[2];
    const float* Wr1 = (const float*)d_in[3];
    const float* b1  = (const float*)d_in[4];
    const float* g1  = (const float*)d_in[5];
    const float* be1 = (const float*)d_in[6];
    const float* Wl2 = (const float*)d_in[7];
    const float* Wr2 = (const float*)d_in[8];
    const float* b2  = (const float*)d_in[9];
    const float* g2  = (const float*)d_in[10];
    const float* be2 = (const float*)d_in[11];
    const float* Wl3 = (const float*)d_in[12];
    const float* Wr3 = (const float*)d_in[13];
    const float* b3  = (const float*)d_in[14];
    float* out = (float*)d_out;

    char* p = (char*)d_ws;
    size_t off = 0;
    auto alloc = [&](size_t bytes) {
        char* r = p + off;
        off = (off + bytes + 255) & ~(size_t)255;
        return r;
    };
    int*            cnt   = (int*)alloc((size_t)N_NODES * 4);
    int*            curs  = (int*)alloc((size_t)N_NODES * 4);
    int*            row   = (int*)alloc((size_t)(N_NODES + 1) * 4);
    int*            parts = (int*)alloc((size_t)SCAN_BLOCKS * 4);
    int*            csrc  = (int*)alloc((size_t)N_EDGES * 4);
    unsigned short* xb    = (unsigned short*)alloc((size_t)N_NODES * 128 * 2);
    unsigned short* mn    = (unsigned short*)alloc((size_t)N_NODES * 128 * 2);
    unsigned short* h1    = (unsigned short*)alloc((size_t)N_NODES * 128 * 2);
    unsigned short* h2    = (unsigned short*)alloc((size_t)N_NODES * 128 * 2);
    unsigned short* wbf   = (unsigned short*)alloc((size_t)81920 * 2);
    float*          cs    = (float*)alloc(256 * 4);   // cs[128] | cq[128] contiguous
    float*          cq    = cs + 128;
    float*          scl   = (float*)alloc(128 * 4);
    float*          shf   = (float*)alloc(128 * 4);
    (void)ws_size; (void)n_in; (void)in_sizes; (void)out_size;

    unsigned short* wl1b = wbf;
    unsigned short* wr1b = wbf + 16384;
    unsigned short* wl2b = wbf + 32768;
    unsigned short* wr2b = wbf + 49152;
    unsigned short* wl3b = wbf + 65536;
    unsigned short* wr3b = wbf + 73728;

    const int EBLK  = (N_EDGES + 255) / 256;       // 3125
    const int NBLK4 = (N_NODES + 3) / 4;           // 12500
    const int GBLK  = (N_NODES + 63) / 64;         // 782
    const int CBLK  = (N_NODES * 32 + 255) / 256;  // 6250

    // casts + CSR build
    cast_x<<<CBLK, 256, 0, stream>>>(x, xb);
    wcast<<<320, 256, 0, stream>>>(Wl1, Wr1, Wl2, Wr2, Wl3, Wr3, wbf);
    hipMemsetAsync(cnt, 0, (size_t)N_NODES * 4, stream);
    count_edges<<<EBLK, 256, 0, stream>>>(ei, cnt);
    partial_sums<<<SCAN_BLOCKS, 256, 0, stream>>>(cnt, parts);
    scan_partials<<<1, 256, 0, stream>>>(parts, row);
    scan_apply<<<SCAN_BLOCKS, 256, 0, stream>>>(cnt, parts, row, curs);
    fill_csr<<<EBLK, 256, 0, stream>>>(ei, curs, csrc);

    // Layer 1
    agg_mean_bf16<<<NBLK4, 256, 0, stream>>>(xb, row, csrc, mn);
    gemm_mfma<128, true><<<GBLK, 256, 0, stream>>>(mn, xb, wl1b, wr1b, b1, h1, nullptr);
    hipMemsetAsync(cs, 0, 256 * 4, stream);
    col_stats_bf16<<<256, 256, 0, stream>>>(h1, cs, cq);
    bn_prep<<<1, 128, 0, stream>>>(cs, cq, g1, be1, scl, shf);
    bn_relu_bf16<<<CBLK, 256, 0, stream>>>(h1, scl, shf);

    // Layer 2
    agg_mean_bf16<<<NBLK4, 256, 0, stream>>>(h1, row, csrc, mn);
    gemm_mfma<128, true><<<GBLK, 256, 0, stream>>>(mn, h1, wl2b, wr2b, b2, h2, nullptr);
    hipMemsetAsync(cs, 0, 256 * 4, stream);
    col_stats_bf16<<<256, 256, 0, stream>>>(h2, cs, cq);
    bn_prep<<<1, 128, 0, stream>>>(cs, cq, g2, be2, scl, shf);
    bn_relu_bf16<<<CBLK, 256, 0, stream>>>(h2, scl, shf);

    // Layer 3 -> f32 d_out
    agg_mean_bf16<<<NBLK4, 256, 0, stream>>>(h2, row, csrc, mn);
    gemm_mfma<64, false><<<GBLK, 256, 0, stream>>>(mn, h2, wl3b, wr3b, b3, nullptr, out);
}

// Round 4
// 421.915 us; speedup vs baseline: 2.0179x; 1.0474x over previous
//
#include <hip/hip_runtime.h>

#define N_NODES 50000
#define N_EDGES 800000
#define BN_EPS 1e-5f
#define SCAN_BLOCKS 196   // ceil(50000/256)
#define PART_SZ 6250      // 50000 / 8 XCDs
#define EDGE_CHUNK 25000  // 800000 / 32 chunks

typedef __bf16 bf16x8 __attribute__((ext_vector_type(8)));
typedef float f32x4 __attribute__((ext_vector_type(4)));

static __device__ __forceinline__ unsigned short f2b(float f) {
    unsigned int u = __float_as_uint(f);
    return (unsigned short)((u + 0x7FFFu + ((u >> 16) & 1u)) >> 16);   // RNE
}
static __device__ __forceinline__ float bl(unsigned int u) { return __uint_as_float(u << 16); }
static __device__ __forceinline__ float bh(unsigned int u) { return __uint_as_float(u & 0xFFFF0000u); }

// ---------------------------------------------------------------------------
// CSR build: count -> 2-level scan -> XCD-partitioned fill
// ---------------------------------------------------------------------------
__global__ void count_edges(const int* __restrict__ ei, int* __restrict__ cnt) {
    int e = blockIdx.x * 256 + threadIdx.x;
    if (e < N_EDGES) atomicAdd(&cnt[ei[N_EDGES + e]], 1);
}

__global__ __launch_bounds__(256) void partial_sums(const int* __restrict__ cnt,
                                                    int* __restrict__ partials) {
    int t = threadIdx.x;
    int i = blockIdx.x * 256 + t;
    int v = (i < N_NODES) ? cnt[i] : 0;
    __shared__ int sm[256];
    sm[t] = v;
    __syncthreads();
    for (int off = 128; off > 0; off >>= 1) {
        if (t < off) sm[t] += sm[t + off];
        __syncthreads();
    }
    if (t == 0) partials[blockIdx.x] = sm[0];
}

__global__ __launch_bounds__(256) void scan_partials(int* __restrict__ partials,
                                                     int* __restrict__ row) {
    __shared__ int sm[256];
    int t = threadIdx.x;
    int v = (t < SCAN_BLOCKS) ? partials[t] : 0;
    sm[t] = v;
    __syncthreads();
    int x = v;
    for (int off = 1; off < 256; off <<= 1) {
        int y = (t >= off) ? sm[t - off] : 0;
        __syncthreads();
        x += y;
        sm[t] = x;
        __syncthreads();
    }
    if (t < SCAN_BLOCKS) partials[t] = x - v;   // exclusive
    if (t == 0) row[N_NODES] = N_EDGES;
}

__global__ __launch_bounds__(256) void scan_apply(const int* __restrict__ cnt,
                                                  const int* __restrict__ partials,
                                                  int* __restrict__ row,
                                                  int* __restrict__ cursor) {
    int t = threadIdx.x;
    int i = blockIdx.x * 256 + t;
    int v = (i < N_NODES) ? cnt[i] : 0;
    __shared__ int sm[256];
    sm[t] = v;
    __syncthreads();
    int x = v;
    for (int off = 1; off < 256; off <<= 1) {
        int y = (t >= off) ? sm[t - off] : 0;
        __syncthreads();
        x += y;
        sm[t] = x;
        __syncthreads();
    }
    int pre = x - v + partials[blockIdx.x];
    if (i < N_NODES) {
        row[i] = pre;
        cursor[i] = pre;
    }
}

// XCD-partitioned fill: block b -> XCD (b&7) owns dst range, scans chunk (b>>3).
// All writes to a csrc region stay on one XCD's L2 -> dense writeback instead
// of 800k cross-XCD partial-line flushes.
__global__ __launch_bounds__(256) void fill_csr_part(const int* __restrict__ ei,
                                                     int* __restrict__ cursor,
                                                     int* __restrict__ csrc) {
    int xcd = blockIdx.x & 7;
    int chunk = blockIdx.x >> 3;
    int lo = xcd * PART_SZ, hi = lo + PART_SZ;
    int e0 = chunk * EDGE_CHUNK;
    int e1 = e0 + EDGE_CHUNK;
    for (int e = e0 + threadIdx.x; e < e1; e += 256) {
        int d = ei[N_EDGES + e];
        if (d >= lo && d < hi) {
            int s = ei[e];
            int p = atomicAdd(&cursor[d], 1);
            csrc[p] = s;
        }
    }
}

// ---------------------------------------------------------------------------
// Casts
// ---------------------------------------------------------------------------
__global__ __launch_bounds__(256) void cast_x(const float* __restrict__ in,
                                              unsigned short* __restrict__ out) {
    int idx = blockIdx.x * 256 + threadIdx.x;          // float4 chunk
    if (idx >= N_NODES * 32) return;
    float4 v = ((const float4*)in)[idx];
    uint2 p;
    p.x = (unsigned int)f2b(v.x) | ((unsigned int)f2b(v.y) << 16);
    p.y = (unsigned int)f2b(v.z) | ((unsigned int)f2b(v.w) << 16);
    ((uint2*)out)[idx] = p;
}

__global__ void wcast(const float* __restrict__ Wl1, const float* __restrict__ Wr1,
                      const float* __restrict__ Wl2, const float* __restrict__ Wr2,
                      const float* __restrict__ Wl3, const float* __restrict__ Wr3,
                      unsigned short* __restrict__ out) {
    int idx = blockIdx.x * 256 + threadIdx.x;
    if (idx >= 81920) return;
    float v;
    if (idx < 16384)       v = Wl1[idx];
    else if (idx < 32768)  v = Wr1[idx - 16384];
    else if (idx < 49152)  v = Wl2[idx - 32768];
    else if (idx < 65536)  v = Wr2[idx - 49152];
    else if (idx < 73728)  v = Wl3[idx - 65536];
    else                   v = Wr3[idx - 73728];
    out[idx] = f2b(v);
}

// ---------------------------------------------------------------------------
// Mean aggregation: half-wave (32 lanes) per node, lane holds uint2 (4 bf16).
// 2 nodes per wave, 8 per 256-block.
// ---------------------------------------------------------------------------
__global__ __launch_bounds__(256) void agg_mean_bf16(const unsigned short* __restrict__ xin,
                                                     const int* __restrict__ row,
                                                     const int* __restrict__ csrc,
                                                     unsigned short* __restrict__ mean) {
    int half = threadIdx.x >> 5;
    int hl = threadIdx.x & 31;
    int node = blockIdx.x * 8 + half;
    if (node >= N_NODES) return;
    int r0 = row[node], r1 = row[node + 1];
    const uint2* x2 = (const uint2*)xin;   // row stride 32 uint2
    float a0 = 0.f, a1 = 0.f, a2 = 0.f, a3 = 0.f;
    int j = r0;
    for (; j + 1 < r1; j += 2) {
        int s0 = csrc[j];
        int s1 = csrc[j + 1];
        uint2 v0 = x2[(size_t)s0 * 32 + hl];
        uint2 v1 = x2[(size_t)s1 * 32 + hl];
        a0 += bl(v0.x) + bl(v1.x);
        a1 += bh(v0.x) + bh(v1.x);
        a2 += bl(v0.y) + bl(v1.y);
        a3 += bh(v0.y) + bh(v1.y);
    }
    if (j < r1) {
        uint2 v = x2[(size_t)csrc[j] * 32 + hl];
        a0 += bl(v.x);
        a1 += bh(v.x);
        a2 += bl(v.y);
        a3 += bh(v.y);
    }
    int deg = r1 - r0;
    float inv = 1.0f / (float)(deg > 1 ? deg : 1);
    uint2 pk;
    pk.x = (unsigned int)f2b(a0 * inv) | ((unsigned int)f2b(a1 * inv) << 16);
    pk.y = (unsigned int)f2b(a2 * inv) | ((unsigned int)f2b(a3 * inv) << 16);
    ((uint2*)mean)[(size_t)node * 32 + hl] = pk;
}

// ---------------------------------------------------------------------------
// MFMA dual-GEMM: out[n][o] = mean[n]·Wl[o] + x[n]·Wr[o] + b[o]
// block = 256 thr (4 waves), 64 rows/block, wave owns 16 rows × O cols.
// ---------------------------------------------------------------------------
template <int O, bool BF16OUT>
__global__ __launch_bounds__(256) void gemm_mfma(const unsigned short* __restrict__ Am,
                                                 const unsigned short* __restrict__ Ax,
                                                 const unsigned short* __restrict__ Wl,
                                                 const unsigned short* __restrict__ Wr,
                                                 const float* __restrict__ bias,
                                                 unsigned short* __restrict__ hout,
                                                 float* __restrict__ fout) {
    constexpr int NF = O / 16;
    int t = threadIdx.x;
    int wv = t >> 6, l = t & 63;
    int lr = l & 15;
    int ko = l >> 4;
    int arow = blockIdx.x * 64 + wv * 16 + lr;
    int ar = arow < N_NODES ? arow : N_NODES - 1;
    const bf16x8* am = (const bf16x8*)(Am + (size_t)ar * 128);
    const bf16x8* ax = (const bf16x8*)(Ax + (size_t)ar * 128);

    f32x4 acc[NF];
#pragma unroll
    for (int nf = 0; nf < NF; ++nf) acc[nf] = (f32x4){0.f, 0.f, 0.f, 0.f};

#pragma unroll
    for (int ks = 0; ks < 4; ++ks) {
        bf16x8 a1 = am[ks * 4 + ko];
        bf16x8 a2 = ax[ks * 4 + ko];
#pragma unroll
        for (int nf = 0; nf < NF; ++nf) {
            const bf16x8* wlp = (const bf16x8*)(Wl + (size_t)(nf * 16 + lr) * 128);
            const bf16x8* wrp = (const bf16x8*)(Wr + (size_t)(nf * 16 + lr) * 128);
            acc[nf] = __builtin_amdgcn_mfma_f32_16x16x32_bf16(a1, wlp[ks * 4 + ko], acc[nf], 0, 0, 0);
            acc[nf] = __builtin_amdgcn_mfma_f32_16x16x32_bf16(a2, wrp[ks * 4 + ko], acc[nf], 0, 0, 0);
        }
    }

    int orow0 = blockIdx.x * 64 + wv * 16 + ko * 4;
#pragma unroll
    for (int nf = 0; nf < NF; ++nf) {
        int col = nf * 16 + lr;
        float bs = bias[col];
#pragma unroll
        for (int j = 0; j < 4; ++j) {
            int r = orow0 + j;
            if (r < N_NODES) {
                float v = acc[nf][j] + bs;
                if (BF16OUT) hout[(size_t)r * 128 + col] = f2b(v);
                else         fout[(size_t)r * 64 + col] = v;
            }
        }
    }
}

// ---------------------------------------------------------------------------
// BN stats over bf16 h
// ---------------------------------------------------------------------------
__global__ __launch_bounds__(256) void col_stats_bf16(const unsigned short* __restrict__ h,
                                                      float* __restrict__ cs,
                                                      float* __restrict__ cq) {
    int t = threadIdx.x;
    int f4 = t & 31;
    int rg = t >> 5;
    float s0 = 0, s1 = 0, s2 = 0, s3 = 0, q0 = 0, q1 = 0, q2 = 0, q3 = 0;
    for (int n = blockIdx.x * 8 + rg; n < N_NODES; n += gridDim.x * 8) {
        uint2 v = ((const uint2*)h)[(size_t)n * 32 + f4];
        float a = bl(v.x), b = bh(v.x), c = bl(v.y), d = bh(v.y);
        s0 += a; s1 += b; s2 += c; s3 += d;
        q0 += a * a; q1 += b * b; q2 += c * c; q3 += d * d;
    }
    __shared__ float4 sb[256], qb[256];
    sb[t] = make_float4(s0, s1, s2, s3);
    qb[t] = make_float4(q0, q1, q2, q3);
    __syncthreads();
    if (t < 32) {
        float4 S = sb[t], Q = qb[t];
        for (int g = 1; g < 8; ++g) {
            float4 s2v = sb[g * 32 + t], q2v = qb[g * 32 + t];
            S.x += s2v.x; S.y += s2v.y; S.z += s2v.z; S.w += s2v.w;
            Q.x += q2v.x; Q.y += q2v.y; Q.z += q2v.z; Q.w += q2v.w;
        }
        atomicAdd(&cs[t * 4 + 0], S.x);
        atomicAdd(&cs[t * 4 + 1], S.y);
        atomicAdd(&cs[t * 4 + 2], S.z);
        atomicAdd(&cs[t * 4 + 3], S.w);
        atomicAdd(&cq[t * 4 + 0], Q.x);
        atomicAdd(&cq[t * 4 + 1], Q.y);
        atomicAdd(&cq[t * 4 + 2], Q.z);
        atomicAdd(&cq[t * 4 + 3], Q.w);
    }
}

__global__ void bn_prep(const float* __restrict__ cs, const float* __restrict__ cq,
                        const float* __restrict__ g, const float* __restrict__ be,
                        float* __restrict__ scale, float* __restrict__ shift) {
    int f = threadIdx.x;
    float mu = cs[f] * (1.0f / N_NODES);
    float var = cq[f] * (1.0f / N_NODES) - mu * mu;
    float sc = g[f] * rsqrtf(var + BN_EPS);
    scale[f] = sc;
    shift[f] = be[f] - mu * sc;
}

__global__ __launch_bounds__(256) void bn_relu_bf16(unsigned short* __restrict__ h,
                                                    const float* __restrict__ scale,
                                                    const float* __restrict__ shift) {
    int idx = blockIdx.x * 256 + threadIdx.x;
    if (idx >= N_NODES * 32) return;
    int f0 = (idx & 31) * 4;
    uint2 v = ((uint2*)h)[idx];
    float a = fmaxf(bl(v.x) * scale[f0 + 0] + shift[f0 + 0], 0.f);
    float b = fmaxf(bh(v.x) * scale[f0 + 1] + shift[f0 + 1], 0.f);
    float c = fmaxf(bl(v.y) * scale[f0 + 2] + shift[f0 + 2], 0.f);
    float d = fmaxf(bh(v.y) * scale[f0 + 3] + shift[f0 + 3], 0.f);
    uint2 p;
    p.x = (unsigned int)f2b(a) | ((unsigned int)f2b(b) << 16);
    p.y = (unsigned int)f2b(c) | ((unsigned int)f2b(d) << 16);
    ((uint2*)h)[idx] = p;
}

// ---------------------------------------------------------------------------
extern "C" void kernel_launch(void* const* d_in, const int* in_sizes, int n_in,
                              void* d_out, int out_size, void* d_ws, size_t ws_size,
                              hipStream_t stream) {
    const float* x   = (const float*)d_in[0];
    const int*   ei  = (const int*)d_in[1];
    const float* Wl1 = (const float*)d_in[2];
    const float* Wr1 = (const float*)d_in[3];
    const float* b1  = (const float*)d_in[4];
    const float* g1  = (const float*)d_in[5];
    const float* be1 = (const float*)d_in[6];
    const float* Wl2 = (const float*)d_in[7];
    const float* Wr2 = (const float*)d_in[8];
    const float* b2  = (const float*)d_in[9];
    const float* g2  = (const float*)d_in[10];
    const float* be2 = (const float*)d_in[11];
    const float* Wl3 = (const float*)d_in[12];
    const float* Wr3 = (const float*)d_in[13];
    const float* b3  = (const float*)d_in[14];
    float* out = (float*)d_out;

    char* p = (char*)d_ws;
    size_t off = 0;
    auto alloc = [&](size_t bytes) {
        char* r = p + off;
        off = (off + bytes + 255) & ~(size_t)255;
        return r;
    };
    int*            cnt   = (int*)alloc((size_t)N_NODES * 4);
    int*            curs  = (int*)alloc((size_t)N_NODES * 4);
    int*            row   = (int*)alloc((size_t)(N_NODES + 1) * 4);
    int*            parts = (int*)alloc((size_t)SCAN_BLOCKS * 4);
    int*            csrc  = (int*)alloc((size_t)N_EDGES * 4);
    unsigned short* xb    = (unsigned short*)alloc((size_t)N_NODES * 128 * 2);
    unsigned short* mn    = (unsigned short*)alloc((size_t)N_NODES * 128 * 2);
    unsigned short* h1    = (unsigned short*)alloc((size_t)N_NODES * 128 * 2);
    unsigned short* h2    = (unsigned short*)alloc((size_t)N_NODES * 128 * 2);
    unsigned short* wbf   = (unsigned short*)alloc((size_t)81920 * 2);
    float*          cs    = (float*)alloc(256 * 4);   // cs[128] | cq[128]
    float*          cq    = cs + 128;
    float*          scl   = (float*)alloc(128 * 4);
    float*          shf   = (float*)alloc(128 * 4);
    (void)ws_size; (void)n_in; (void)in_sizes; (void)out_size;

    unsigned short* wl1b = wbf;
    unsigned short* wr1b = wbf + 16384;
    unsigned short* wl2b = wbf + 32768;
    unsigned short* wr2b = wbf + 49152;
    unsigned short* wl3b = wbf + 65536;
    unsigned short* wr3b = wbf + 73728;

    const int EBLK  = (N_EDGES + 255) / 256;       // 3125
    const int NBLK8 = (N_NODES + 7) / 8;           // 6250
    const int GBLK  = (N_NODES + 63) / 64;         // 782
    const int CBLK  = (N_NODES * 32 + 255) / 256;  // 6250

    // casts + CSR build
    cast_x<<<CBLK, 256, 0, stream>>>(x, xb);
    wcast<<<320, 256, 0, stream>>>(Wl1, Wr1, Wl2, Wr2, Wl3, Wr3, wbf);
    hipMemsetAsync(cnt, 0, (size_t)N_NODES * 4, stream);
    count_edges<<<EBLK, 256, 0, stream>>>(ei, cnt);
    partial_sums<<<SCAN_BLOCKS, 256, 0, stream>>>(cnt, parts);
    scan_partials<<<1, 256, 0, stream>>>(parts, row);
    scan_apply<<<SCAN_BLOCKS, 256, 0, stream>>>(cnt, parts, row, curs);
    fill_csr_part<<<256, 256, 0, stream>>>(ei, curs, csrc);

    // Layer 1
    agg_mean_bf16<<<NBLK8, 256, 0, stream>>>(xb, row, csrc, mn);
    gemm_mfma<128, true><<<GBLK, 256, 0, stream>>>(mn, xb, wl1b, wr1b, b1, h1, nullptr);
    hipMemsetAsync(cs, 0, 256 * 4, stream);
    col_stats_bf16<<<256, 256, 0, stream>>>(h1, cs, cq);
    bn_prep<<<1, 128, 0, stream>>>(cs, cq, g1, be1, scl, shf);
    bn_relu_bf16<<<CBLK, 256, 0, stream>>>(h1, scl, shf);

    // Layer 2
    agg_mean_bf16<<<NBLK8, 256, 0, stream>>>(h1, row, csrc, mn);
    gemm_mfma<128, true><<<GBLK, 256, 0, stream>>>(mn, h1, wl2b, wr2b, b2, h2, nullptr);
    hipMemsetAsync(cs, 0, 256 * 4, stream);
    col_stats_bf16<<<256, 256, 0, stream>>>(h2, cs, cq);
    bn_prep<<<1, 128, 0, stream>>>(cs, cq, g2, be2, scl, shf);
    bn_relu_bf16<<<CBLK, 256, 0, stream>>>(h2, scl, shf);

    // Layer 3 -> f32 d_out
    agg_mean_bf16<<<NBLK8, 256, 0, stream>>>(h2, row, csrc, mn);
    gemm_mfma<64, false><<<GBLK, 256, 0, stream>>>(mn, h2, wl3b, wr3b, b3, nullptr, out);
}

// Round 5
// 298.519 us; speedup vs baseline: 2.8520x; 1.4134x over previous
//
#include <hip/hip_runtime.h>

#define N_NODES 50000
#define N_EDGES 800000
#define BN_EPS 1e-5f
#define NB 196          // dst buckets: bucket = dst >> 8
#define BCAP 5120       // bucket capacity (avg 4082, sigma ~64)
#define SCAT_BLOCKS 100 // 8000 edges per block

typedef __bf16 bf16x8 __attribute__((ext_vector_type(8)));
typedef float f32x4 __attribute__((ext_vector_type(4)));

static __device__ __forceinline__ unsigned short f2b(float f) {
    unsigned int u = __float_as_uint(f);
    return (unsigned short)((u + 0x7FFFu + ((u >> 16) & 1u)) >> 16);   // RNE
}
static __device__ __forceinline__ float bl(unsigned int u) { return __uint_as_float(u << 16); }
static __device__ __forceinline__ float bh(unsigned int u) { return __uint_as_float(u & 0xFFFF0000u); }

// ---------------------------------------------------------------------------
// CSR build via dense-write bucket sort
// ---------------------------------------------------------------------------
__global__ void init_gcur(int* __restrict__ gcur) {
    int t = threadIdx.x;
    if (t < NB) gcur[t] = t * BCAP;
}

__global__ __launch_bounds__(256) void bucket_scatter(const int* __restrict__ ei,
                                                      int* __restrict__ gcur,
                                                      unsigned int* __restrict__ bdata) {
    __shared__ int hist[NB];
    __shared__ int lcur[NB];
    int t = threadIdx.x;
    if (t < NB) hist[t] = 0;
    __syncthreads();
    int e0 = blockIdx.x * 8000;
    for (int i = t; i < 8000; i += 256) {
        int d = ei[N_EDGES + e0 + i];
        atomicAdd(&hist[d >> 8], 1);
    }
    __syncthreads();
    if (t < NB) lcur[t] = atomicAdd(&gcur[t], hist[t]);
    __syncthreads();
    for (int i = t; i < 8000; i += 256) {
        int d = ei[N_EDGES + e0 + i];
        int s = ei[e0 + i];
        int b = d >> 8;
        int p = atomicAdd(&lcur[b], 1);
        if (p < (b + 1) * BCAP)                       // capacity guard
            bdata[p] = (unsigned int)s | ((unsigned int)(d & 255) << 16);
    }
}

__global__ __launch_bounds__(256) void scan_buckets(const int* __restrict__ gcur,
                                                    int* __restrict__ bbase,
                                                    int* __restrict__ row) {
    __shared__ int sm[256];
    int t = threadIdx.x;
    int v = 0;
    if (t < NB) {
        v = gcur[t] - t * BCAP;
        if (v > BCAP) v = BCAP;
    }
    sm[t] = v;
    __syncthreads();
    int x = v;
    for (int off = 1; off < 256; off <<= 1) {
        int y = (t >= off) ? sm[t - off] : 0;
        __syncthreads();
        x += y;
        sm[t] = x;
        __syncthreads();
    }
    if (t < NB) bbase[t] = x - v;   // exclusive
    if (t == 0) row[N_NODES] = N_EDGES;
}

// One block per bucket: local count + scan + fill, all writes dense & block-local.
__global__ __launch_bounds__(256) void bucket_fill(const unsigned int* __restrict__ bdata,
                                                   const int* __restrict__ gcur,
                                                   const int* __restrict__ bbase,
                                                   int* __restrict__ row,
                                                   int* __restrict__ csrc) {
    __shared__ unsigned int ent[BCAP];
    __shared__ int lcnt[256];
    __shared__ int sm[256];
    __shared__ int cur[256];
    int b = blockIdx.x;
    int t = threadIdx.x;
    int cnt = gcur[b] - b * BCAP;
    if (cnt > BCAP) cnt = BCAP;
    int base = bbase[b];
    for (int i = t; i < cnt; i += 256) ent[i] = bdata[b * BCAP + i];
    lcnt[t] = 0;
    __syncthreads();
    for (int i = t; i < cnt; i += 256) atomicAdd(&lcnt[(ent[i] >> 16) & 255], 1);
    __syncthreads();
    int v = lcnt[t];
    sm[t] = v;
    __syncthreads();
    int x = v;
    for (int off = 1; off < 256; off <<= 1) {
        int y = (t >= off) ? sm[t - off] : 0;
        __syncthreads();
        x += y;
        sm[t] = x;
        __syncthreads();
    }
    int pre = x - v;
    int node = b * 256 + t;
    if (node < N_NODES) row[node] = base + pre;
    cur[t] = base + pre;
    __syncthreads();
    for (int i = t; i < cnt; i += 256) {
        unsigned int e = ent[i];
        int p = atomicAdd(&cur[(e >> 16) & 255], 1);
        csrc[p] = (int)(e & 0xFFFFu);
    }
}

// ---------------------------------------------------------------------------
// Casts
// ---------------------------------------------------------------------------
__global__ __launch_bounds__(256) void cast_x(const float* __restrict__ in,
                                              unsigned short* __restrict__ out) {
    int idx = blockIdx.x * 256 + threadIdx.x;          // float4 chunk
    if (idx >= N_NODES * 32) return;
    float4 v = ((const float4*)in)[idx];
    uint2 p;
    p.x = (unsigned int)f2b(v.x) | ((unsigned int)f2b(v.y) << 16);
    p.y = (unsigned int)f2b(v.z) | ((unsigned int)f2b(v.w) << 16);
    ((uint2*)out)[idx] = p;
}

__global__ void wcast(const float* __restrict__ Wl1, const float* __restrict__ Wr1,
                      const float* __restrict__ Wl2, const float* __restrict__ Wr2,
                      const float* __restrict__ Wl3, const float* __restrict__ Wr3,
                      unsigned short* __restrict__ out) {
    int idx = blockIdx.x * 256 + threadIdx.x;
    if (idx >= 81920) return;
    float v;
    if (idx < 16384)       v = Wl1[idx];
    else if (idx < 32768)  v = Wr1[idx - 16384];
    else if (idx < 49152)  v = Wl2[idx - 32768];
    else if (idx < 65536)  v = Wr2[idx - 49152];
    else if (idx < 73728)  v = Wl3[idx - 65536];
    else                   v = Wr3[idx - 73728];
    out[idx] = f2b(v);
}

// ---------------------------------------------------------------------------
// Mean aggregation: half-wave (32 lanes) per node, lane holds uint2 (4 bf16).
// ACT: apply relu(h*scale+shift) to each gathered element (folds BN+ReLU of
// the previous layer into the gather).
// ---------------------------------------------------------------------------
template <bool ACT>
__global__ __launch_bounds__(256) void agg_mean_bf16(const unsigned short* __restrict__ xin,
                                                     const int* __restrict__ row,
                                                     const int* __restrict__ csrc,
                                                     const float* __restrict__ scl,
                                                     const float* __restrict__ shf,
                                                     unsigned short* __restrict__ mean) {
    int half = threadIdx.x >> 5;
    int hl = threadIdx.x & 31;
    int node = blockIdx.x * 8 + half;
    if (node >= N_NODES) return;
    float4 sc{}, sh{};
    if (ACT) {
        sc = ((const float4*)scl)[hl];
        sh = ((const float4*)shf)[hl];
    }
    int r0 = row[node], r1 = row[node + 1];
    const uint2* x2 = (const uint2*)xin;   // row stride 32 uint2
    float a0 = 0.f, a1 = 0.f, a2 = 0.f, a3 = 0.f;
    auto val = [&](float raw, float s, float h) {
        return ACT ? fmaxf(fmaf(raw, s, h), 0.f) : raw;
    };
    int j = r0;
    for (; j + 1 < r1; j += 2) {
        int s0 = csrc[j];
        int s1 = csrc[j + 1];
        uint2 v0 = x2[(size_t)s0 * 32 + hl];
        uint2 v1 = x2[(size_t)s1 * 32 + hl];
        a0 += val(bl(v0.x), sc.x, sh.x) + val(bl(v1.x), sc.x, sh.x);
        a1 += val(bh(v0.x), sc.y, sh.y) + val(bh(v1.x), sc.y, sh.y);
        a2 += val(bl(v0.y), sc.z, sh.z) + val(bl(v1.y), sc.z, sh.z);
        a3 += val(bh(v0.y), sc.w, sh.w) + val(bh(v1.y), sc.w, sh.w);
    }
    if (j < r1) {
        uint2 v = x2[(size_t)csrc[j] * 32 + hl];
        a0 += val(bl(v.x), sc.x, sh.x);
        a1 += val(bh(v.x), sc.y, sh.y);
        a2 += val(bl(v.y), sc.z, sh.z);
        a3 += val(bh(v.y), sc.w, sh.w);
    }
    int deg = r1 - r0;
    float inv = 1.0f / (float)(deg > 1 ? deg : 1);
    uint2 pk;
    pk.x = (unsigned int)f2b(a0 * inv) | ((unsigned int)f2b(a1 * inv) << 16);
    pk.y = (unsigned int)f2b(a2 * inv) | ((unsigned int)f2b(a3 * inv) << 16);
    ((uint2*)mean)[(size_t)node * 32 + hl] = pk;
}

// ---------------------------------------------------------------------------
// MFMA dual-GEMM with optional fused input-activation (ACTX on the Ax side,
// prev layer's BN+ReLU) and fused column stats (STATS -> cs/cq atomics).
// ---------------------------------------------------------------------------
template <int O, bool BF16OUT, bool STATS, bool ACTX>
__global__ __launch_bounds__(256) void gemm_mfma(const unsigned short* __restrict__ Am,
                                                 const unsigned short* __restrict__ Ax,
                                                 const unsigned short* __restrict__ Wl,
                                                 const unsigned short* __restrict__ Wr,
                                                 const float* __restrict__ bias,
                                                 const float* __restrict__ sclx,
                                                 const float* __restrict__ shfx,
                                                 unsigned short* __restrict__ hout,
                                                 float* __restrict__ fout,
                                                 float* __restrict__ cs,
                                                 float* __restrict__ cq) {
    constexpr int NF = O / 16;
    __shared__ float colsum[O], colsq[O];
    int t = threadIdx.x;
    int wv = t >> 6, l = t & 63;
    int lr = l & 15;
    int ko = l >> 4;
    if (STATS && t < O) {
        colsum[t] = 0.f;
        colsq[t] = 0.f;
    }
    int arow = blockIdx.x * 64 + wv * 16 + lr;
    int ar = arow < N_NODES ? arow : N_NODES - 1;
    const bf16x8* am = (const bf16x8*)(Am + (size_t)ar * 128);
    const bf16x8* ax = (const bf16x8*)(Ax + (size_t)ar * 128);
    if (STATS) __syncthreads();

    f32x4 acc[NF];
#pragma unroll
    for (int nf = 0; nf < NF; ++nf) acc[nf] = (f32x4){0.f, 0.f, 0.f, 0.f};

#pragma unroll
    for (int ks = 0; ks < 4; ++ks) {
        bf16x8 a1 = am[ks * 4 + ko];
        bf16x8 a2 = ax[ks * 4 + ko];
        if (ACTX) {
            uint4 u = *(reinterpret_cast<uint4*>(&a2));
            int f0 = (ks * 4 + ko) * 8;
            const float* sp = sclx + f0;
            const float* hp = shfx + f0;
            float e0 = fmaxf(fmaf(bl(u.x), sp[0], hp[0]), 0.f);
            float e1 = fmaxf(fmaf(bh(u.x), sp[1], hp[1]), 0.f);
            float e2 = fmaxf(fmaf(bl(u.y), sp[2], hp[2]), 0.f);
            float e3 = fmaxf(fmaf(bh(u.y), sp[3], hp[3]), 0.f);
            float e4 = fmaxf(fmaf(bl(u.z), sp[4], hp[4]), 0.f);
            float e5 = fmaxf(fmaf(bh(u.z), sp[5], hp[5]), 0.f);
            float e6 = fmaxf(fmaf(bl(u.w), sp[6], hp[6]), 0.f);
            float e7 = fmaxf(fmaf(bh(u.w), sp[7], hp[7]), 0.f);
            uint4 r;
            r.x = (unsigned int)f2b(e0) | ((unsigned int)f2b(e1) << 16);
            r.y = (unsigned int)f2b(e2) | ((unsigned int)f2b(e3) << 16);
            r.z = (unsigned int)f2b(e4) | ((unsigned int)f2b(e5) << 16);
            r.w = (unsigned int)f2b(e6) | ((unsigned int)f2b(e7) << 16);
            a2 = *(reinterpret_cast<bf16x8*>(&r));
        }
#pragma unroll
        for (int nf = 0; nf < NF; ++nf) {
            const bf16x8* wlp = (const bf16x8*)(Wl + (size_t)(nf * 16 + lr) * 128);
            const bf16x8* wrp = (const bf16x8*)(Wr + (size_t)(nf * 16 + lr) * 128);
            acc[nf] = __builtin_amdgcn_mfma_f32_16x16x32_bf16(a1, wlp[ks * 4 + ko], acc[nf], 0, 0, 0);
            acc[nf] = __builtin_amdgcn_mfma_f32_16x16x32_bf16(a2, wrp[ks * 4 + ko], acc[nf], 0, 0, 0);
        }
    }

    // C/D layout: col = lane&15 (within frag), row = ko*4 + reg
    int orow0 = blockIdx.x * 64 + wv * 16 + ko * 4;
#pragma unroll
    for (int nf = 0; nf < NF; ++nf) {
        int col = nf * 16 + lr;
        float bs = bias[col];
        float s = 0.f, q = 0.f;
#pragma unroll
        for (int j = 0; j < 4; ++j) {
            int r = orow0 + j;
            if (r < N_NODES) {
                float v = acc[nf][j] + bs;
                if (BF16OUT) hout[(size_t)r * 128 + col] = f2b(v);
                else         fout[(size_t)r * 64 + col] = v;
                s += v;
                q += v * v;
            }
        }
        if (STATS) {
            s += __shfl_xor(s, 16);
            s += __shfl_xor(s, 32);
            q += __shfl_xor(q, 16);
            q += __shfl_xor(q, 32);
            if (ko == 0) {
                atomicAdd(&colsum[col], s);
                atomicAdd(&colsq[col], q);
            }
        }
    }
    if (STATS) {
        __syncthreads();
        if (t < O) {
            atomicAdd(&cs[t], colsum[t]);
            atomicAdd(&cq[t], colsq[t]);
        }
    }
}

__global__ void bn_prep(const float* __restrict__ cs, const float* __restrict__ cq,
                        const float* __restrict__ g, const float* __restrict__ be,
                        float* __restrict__ scale, float* __restrict__ shift) {
    int f = threadIdx.x;
    float mu = cs[f] * (1.0f / N_NODES);
    float var = cq[f] * (1.0f / N_NODES) - mu * mu;
    float sc = g[f] * rsqrtf(var + BN_EPS);
    scale[f] = sc;
    shift[f] = be[f] - mu * sc;
}

// ---------------------------------------------------------------------------
extern "C" void kernel_launch(void* const* d_in, const int* in_sizes, int n_in,
                              void* d_out, int out_size, void* d_ws, size_t ws_size,
                              hipStream_t stream) {
    const float* x   = (const float*)d_in[0];
    const int*   ei  = (const int*)d_in[1];
    const float* Wl1 = (const float*)d_in[2];
    const float* Wr1 = (const float*)d_in[3];
    const float* b1  = (const float*)d_in[4];
    const float* g1  = (const float*)d_in[5];
    const float* be1 = (const float*)d_in[6];
    const float* Wl2 = (const float*)d_in[7];
    const float* Wr2 = (const float*)d_in[8];
    const float* b2  = (const float*)d_in[9];
    const float* g2  = (const float*)d_in[10];
    const float* be2 = (const float*)d_in[11];
    const float* Wl3 = (const float*)d_in[12];
    const float* Wr3 = (const float*)d_in[13];
    const float* b3  = (const float*)d_in[14];
    float* out = (float*)d_out;

    char* p = (char*)d_ws;
    size_t off = 0;
    auto alloc = [&](size_t bytes) {
        char* r = p + off;
        off = (off + bytes + 255) & ~(size_t)255;
        return r;
    };
    int*            gcur  = (int*)alloc((size_t)NB * 4);
    int*            bbase = (int*)alloc((size_t)NB * 4);
    unsigned int*   bdata = (unsigned int*)alloc((size_t)NB * BCAP * 4);
    int*            row   = (int*)alloc((size_t)(N_NODES + 1) * 4);
    int*            csrc  = (int*)alloc((size_t)N_EDGES * 4);
    unsigned short* xb    = (unsigned short*)alloc((size_t)N_NODES * 128 * 2);
    unsigned short* mn    = (unsigned short*)alloc((size_t)N_NODES * 128 * 2);
    unsigned short* h1    = (unsigned short*)alloc((size_t)N_NODES * 128 * 2);
    unsigned short* h2    = (unsigned short*)alloc((size_t)N_NODES * 128 * 2);
    unsigned short* wbf   = (unsigned short*)alloc((size_t)81920 * 2);
    float*          cs    = (float*)alloc(256 * 4);   // cs[128] | cq[128]
    float*          cq    = cs + 128;
    float*          scl1  = (float*)alloc(128 * 4);
    float*          shf1  = (float*)alloc(128 * 4);
    float*          scl2  = (float*)alloc(128 * 4);
    float*          shf2  = (float*)alloc(128 * 4);
    (void)ws_size; (void)n_in; (void)in_sizes; (void)out_size;

    unsigned short* wl1b = wbf;
    unsigned short* wr1b = wbf + 16384;
    unsigned short* wl2b = wbf + 32768;
    unsigned short* wr2b = wbf + 49152;
    unsigned short* wl3b = wbf + 65536;
    unsigned short* wr3b = wbf + 73728;

    const int NBLK8 = (N_NODES + 7) / 8;           // 6250
    const int GBLK  = (N_NODES + 63) / 64;         // 782
    const int CBLK  = (N_NODES * 32 + 255) / 256;  // 6250

    // casts + CSR build (dense-write bucket sort)
    cast_x<<<CBLK, 256, 0, stream>>>(x, xb);
    wcast<<<320, 256, 0, stream>>>(Wl1, Wr1, Wl2, Wr2, Wl3, Wr3, wbf);
    init_gcur<<<1, 256, 0, stream>>>(gcur);
    bucket_scatter<<<SCAT_BLOCKS, 256, 0, stream>>>(ei, gcur, bdata);
    scan_buckets<<<1, 256, 0, stream>>>(gcur, bbase, row);
    bucket_fill<<<NB, 256, 0, stream>>>(bdata, gcur, bbase, row, csrc);

    // Layer 1
    agg_mean_bf16<false><<<NBLK8, 256, 0, stream>>>(xb, row, csrc, nullptr, nullptr, mn);
    hipMemsetAsync(cs, 0, 256 * 4, stream);
    gemm_mfma<128, true, true, false><<<GBLK, 256, 0, stream>>>(
        mn, xb, wl1b, wr1b, b1, nullptr, nullptr, h1, nullptr, cs, cq);
    bn_prep<<<1, 128, 0, stream>>>(cs, cq, g1, be1, scl1, shf1);

    // Layer 2 (h1 raw; BN1+ReLU folded into consumers)
    agg_mean_bf16<true><<<NBLK8, 256, 0, stream>>>(h1, row, csrc, scl1, shf1, mn);
    hipMemsetAsync(cs, 0, 256 * 4, stream);
    gemm_mfma<128, true, true, true><<<GBLK, 256, 0, stream>>>(
        mn, h1, wl2b, wr2b, b2, scl1, shf1, h2, nullptr, cs, cq);
    bn_prep<<<1, 128, 0, stream>>>(cs, cq, g2, be2, scl2, shf2);

    // Layer 3 (h2 raw; BN2+ReLU folded into consumers) -> f32 d_out
    agg_mean_bf16<true><<<NBLK8, 256, 0, stream>>>(h2, row, csrc, scl2, shf2, mn);
    gemm_mfma<64, false, false, true><<<GBLK, 256, 0, stream>>>(
        mn, h2, wl3b, wr3b, b3, scl2, shf2, nullptr, out, nullptr, nullptr);
}

// Round 6
// 242.998 us; speedup vs baseline: 3.5037x; 1.2285x over previous
//
#include <hip/hip_runtime.h>

#define N_NODES 50000
#define N_EDGES 800000
#define BN_EPS 1e-5f
#define NB 196          // dst buckets: bucket = dst >> 8
#define BCAP 5120       // bucket capacity (avg 4082, sigma ~64)
#define SCAT_BLOCKS 100 // 8000 edges per block

typedef __bf16 bf16x8 __attribute__((ext_vector_type(8)));
typedef float f32x4 __attribute__((ext_vector_type(4)));

static __device__ __forceinline__ unsigned short f2b(float f) {
    unsigned int u = __float_as_uint(f);
    return (unsigned short)((u + 0x7FFFu + ((u >> 16) & 1u)) >> 16);   // RNE
}
static __device__ __forceinline__ float bl(unsigned int u) { return __uint_as_float(u << 16); }
static __device__ __forceinline__ float bh(unsigned int u) { return __uint_as_float(u & 0xFFFF0000u); }

// ---------------------------------------------------------------------------
// CSR build via dense-write bucket sort
// ---------------------------------------------------------------------------
__global__ void init_gcur(int* __restrict__ gcur) {
    int t = threadIdx.x;
    if (t < NB) gcur[t] = t * BCAP;
}

__global__ __launch_bounds__(256) void bucket_scatter(const int* __restrict__ ei,
                                                      int* __restrict__ gcur,
                                                      unsigned int* __restrict__ bdata) {
    __shared__ int hist[NB];
    __shared__ int lcur[NB];
    int t = threadIdx.x;
    if (t < NB) hist[t] = 0;
    __syncthreads();
    int e0 = blockIdx.x * 8000;
    for (int i = t; i < 8000; i += 256) {
        int d = ei[N_EDGES + e0 + i];
        atomicAdd(&hist[d >> 8], 1);
    }
    __syncthreads();
    if (t < NB) lcur[t] = atomicAdd(&gcur[t], hist[t]);
    __syncthreads();
    for (int i = t; i < 8000; i += 256) {
        int d = ei[N_EDGES + e0 + i];
        int s = ei[e0 + i];
        int b = d >> 8;
        int p = atomicAdd(&lcur[b], 1);
        if (p < (b + 1) * BCAP)                       // capacity guard
            bdata[p] = (unsigned int)s | ((unsigned int)(d & 255) << 16);
    }
}

__global__ __launch_bounds__(256) void scan_buckets(const int* __restrict__ gcur,
                                                    int* __restrict__ bbase,
                                                    int* __restrict__ row) {
    __shared__ int sm[256];
    int t = threadIdx.x;
    int v = 0;
    if (t < NB) {
        v = gcur[t] - t * BCAP;
        if (v > BCAP) v = BCAP;
    }
    sm[t] = v;
    __syncthreads();
    int x = v;
    for (int off = 1; off < 256; off <<= 1) {
        int y = (t >= off) ? sm[t - off] : 0;
        __syncthreads();
        x += y;
        sm[t] = x;
        __syncthreads();
    }
    if (t < NB) bbase[t] = x - v;   // exclusive
    if (t == 0) row[N_NODES] = N_EDGES;
}

// One block per bucket: local count + scan + fill, all writes dense & block-local.
__global__ __launch_bounds__(256) void bucket_fill(const unsigned int* __restrict__ bdata,
                                                   const int* __restrict__ gcur,
                                                   const int* __restrict__ bbase,
                                                   int* __restrict__ row,
                                                   int* __restrict__ csrc) {
    __shared__ unsigned int ent[BCAP];
    __shared__ int lcnt[256];
    __shared__ int sm[256];
    __shared__ int cur[256];
    int b = blockIdx.x;
    int t = threadIdx.x;
    int cnt = gcur[b] - b * BCAP;
    if (cnt > BCAP) cnt = BCAP;
    int base = bbase[b];
    for (int i = t; i < cnt; i += 256) ent[i] = bdata[b * BCAP + i];
    lcnt[t] = 0;
    __syncthreads();
    for (int i = t; i < cnt; i += 256) atomicAdd(&lcnt[(ent[i] >> 16) & 255], 1);
    __syncthreads();
    int v = lcnt[t];
    sm[t] = v;
    __syncthreads();
    int x = v;
    for (int off = 1; off < 256; off <<= 1) {
        int y = (t >= off) ? sm[t - off] : 0;
        __syncthreads();
        x += y;
        sm[t] = x;
        __syncthreads();
    }
    int pre = x - v;
    int node = b * 256 + t;
    if (node < N_NODES) row[node] = base + pre;
    cur[t] = base + pre;
    __syncthreads();
    for (int i = t; i < cnt; i += 256) {
        unsigned int e = ent[i];
        int p = atomicAdd(&cur[(e >> 16) & 255], 1);
        csrc[p] = (int)(e & 0xFFFFu);
    }
}

// ---------------------------------------------------------------------------
// Casts
// ---------------------------------------------------------------------------
__global__ __launch_bounds__(256) void cast_x(const float* __restrict__ in,
                                              unsigned short* __restrict__ out) {
    int idx = blockIdx.x * 256 + threadIdx.x;          // float4 chunk
    if (idx >= N_NODES * 32) return;
    float4 v = ((const float4*)in)[idx];
    uint2 p;
    p.x = (unsigned int)f2b(v.x) | ((unsigned int)f2b(v.y) << 16);
    p.y = (unsigned int)f2b(v.z) | ((unsigned int)f2b(v.w) << 16);
    ((uint2*)out)[idx] = p;
}

__global__ void wcast(const float* __restrict__ Wl1, const float* __restrict__ Wr1,
                      const float* __restrict__ Wl2, const float* __restrict__ Wr2,
                      const float* __restrict__ Wl3, const float* __restrict__ Wr3,
                      unsigned short* __restrict__ out) {
    int idx = blockIdx.x * 256 + threadIdx.x;
    if (idx >= 81920) return;
    float v;
    if (idx < 16384)       v = Wl1[idx];
    else if (idx < 32768)  v = Wr1[idx - 16384];
    else if (idx < 49152)  v = Wl2[idx - 32768];
    else if (idx < 65536)  v = Wr2[idx - 49152];
    else if (idx < 73728)  v = Wl3[idx - 65536];
    else                   v = Wr3[idx - 73728];
    out[idx] = f2b(v);
}

// ---------------------------------------------------------------------------
// Mean aggregation: half-wave (32 lanes) per node, lane holds uint2 (4 bf16).
// ACT: apply relu(h*scale+shift) to each gathered element.
// ---------------------------------------------------------------------------
template <bool ACT>
__global__ __launch_bounds__(256) void agg_mean_bf16(const unsigned short* __restrict__ xin,
                                                     const int* __restrict__ row,
                                                     const int* __restrict__ csrc,
                                                     const float* __restrict__ scl,
                                                     const float* __restrict__ shf,
                                                     unsigned short* __restrict__ mean) {
    int half = threadIdx.x >> 5;
    int hl = threadIdx.x & 31;
    int node = blockIdx.x * 8 + half;
    if (node >= N_NODES) return;
    float4 sc{}, sh{};
    if (ACT) {
        sc = ((const float4*)scl)[hl];
        sh = ((const float4*)shf)[hl];
    }
    int r0 = row[node], r1 = row[node + 1];
    const uint2* x2 = (const uint2*)xin;   // row stride 32 uint2
    float a0 = 0.f, a1 = 0.f, a2 = 0.f, a3 = 0.f;
    auto val = [&](float raw, float s, float h) {
        return ACT ? fmaxf(fmaf(raw, s, h), 0.f) : raw;
    };
    int j = r0;
    for (; j + 1 < r1; j += 2) {
        int s0 = csrc[j];
        int s1 = csrc[j + 1];
        uint2 v0 = x2[(size_t)s0 * 32 + hl];
        uint2 v1 = x2[(size_t)s1 * 32 + hl];
        a0 += val(bl(v0.x), sc.x, sh.x) + val(bl(v1.x), sc.x, sh.x);
        a1 += val(bh(v0.x), sc.y, sh.y) + val(bh(v1.x), sc.y, sh.y);
        a2 += val(bl(v0.y), sc.z, sh.z) + val(bl(v1.y), sc.z, sh.z);
        a3 += val(bh(v0.y), sc.w, sh.w) + val(bh(v1.y), sc.w, sh.w);
    }
    if (j < r1) {
        uint2 v = x2[(size_t)csrc[j] * 32 + hl];
        a0 += val(bl(v.x), sc.x, sh.x);
        a1 += val(bh(v.x), sc.y, sh.y);
        a2 += val(bl(v.y), sc.z, sh.z);
        a3 += val(bh(v.y), sc.w, sh.w);
    }
    int deg = r1 - r0;
    float inv = 1.0f / (float)(deg > 1 ? deg : 1);
    uint2 pk;
    pk.x = (unsigned int)f2b(a0 * inv) | ((unsigned int)f2b(a1 * inv) << 16);
    pk.y = (unsigned int)f2b(a2 * inv) | ((unsigned int)f2b(a3 * inv) << 16);
    ((uint2*)mean)[(size_t)node * 32 + hl] = pk;
}

// ---------------------------------------------------------------------------
// MFMA dual-GEMM, LDS-staged weights + register A fragments.
// Block = 256 thr (4 waves), 128 rows/block (32/wave as 2 row-tiles).
// Weights staged fragment-ordered in LDS: chunk c=((m*NF+nf)*4+ks), lane l
// holds W_m[nf*16+(l&15)][ks*32+(l>>4)*8 .. +8] at wlds[c*64+l] -> each lane
// reads its own 16B => conflict-free ds_read_b128, each frag feeds 2 MFMAs.
// ---------------------------------------------------------------------------
template <int O, bool BF16OUT, bool STATS, bool ACTX>
__global__ __launch_bounds__(256) void gemm_mfma(const unsigned short* __restrict__ Am,
                                                 const unsigned short* __restrict__ Ax,
                                                 const unsigned short* __restrict__ Wl,
                                                 const unsigned short* __restrict__ Wr,
                                                 const float* __restrict__ bias,
                                                 const float* __restrict__ sclx,
                                                 const float* __restrict__ shfx,
                                                 unsigned short* __restrict__ hout,
                                                 float* __restrict__ fout,
                                                 float* __restrict__ cs,
                                                 float* __restrict__ cq) {
    constexpr int NF = O / 16;
    constexpr int NCH = 2 * NF * 4;          // 1KB fragment chunks
    __shared__ uint4 wlds[NCH * 64];
    __shared__ float colsum[O], colsq[O];
    int t = threadIdx.x;
    int wv = t >> 6, l = t & 63;
    int lr = l & 15;
    int ko = l >> 4;

    if (STATS && t < O) {
        colsum[t] = 0.f;
        colsq[t] = 0.f;
    }

    // ---- A fragments -> registers ----
    int rbase = blockIdx.x * 128 + wv * 32;
    bf16x8 a1[2][4], a2[2][4];
#pragma unroll
    for (int tt = 0; tt < 2; ++tt) {
        int arow = rbase + tt * 16 + lr;
        int ar = arow < N_NODES ? arow : N_NODES - 1;
        const bf16x8* am = (const bf16x8*)(Am + (size_t)ar * 128);
        const bf16x8* ax = (const bf16x8*)(Ax + (size_t)ar * 128);
#pragma unroll
        for (int ks = 0; ks < 4; ++ks) {
            a1[tt][ks] = am[ks * 4 + ko];
            a2[tt][ks] = ax[ks * 4 + ko];
        }
    }

    // ---- stage weights to LDS, fragment-ordered ----
#pragma unroll
    for (int i = 0; i < NCH / 4; ++i) {
        int c = wv * (NCH / 4) + i;
        int m = c / (NF * 4);
        int nf = (c >> 2) & (NF - 1);
        int ks = c & 3;
        const unsigned short* W = m ? Wr : Wl;
        wlds[c * 64 + l] = *(const uint4*)(W + (size_t)(nf * 16 + lr) * 128 + ks * 32 + ko * 8);
    }

    // ---- in-register BN+ReLU on Ax fragments ----
    if (ACTX) {
#pragma unroll
        for (int ks = 0; ks < 4; ++ks) {
            int f0 = ks * 32 + ko * 8;
            float4 s0 = *(const float4*)(sclx + f0);
            float4 s1 = *(const float4*)(sclx + f0 + 4);
            float4 h0 = *(const float4*)(shfx + f0);
            float4 h1 = *(const float4*)(shfx + f0 + 4);
#pragma unroll
            for (int tt = 0; tt < 2; ++tt) {
                uint4 u = *(uint4*)&a2[tt][ks];
                uint4 r;
                float e0 = fmaxf(fmaf(bl(u.x), s0.x, h0.x), 0.f);
                float e1 = fmaxf(fmaf(bh(u.x), s0.y, h0.y), 0.f);
                float e2 = fmaxf(fmaf(bl(u.y), s0.z, h0.z), 0.f);
                float e3 = fmaxf(fmaf(bh(u.y), s0.w, h0.w), 0.f);
                float e4 = fmaxf(fmaf(bl(u.z), s1.x, h1.x), 0.f);
                float e5 = fmaxf(fmaf(bh(u.z), s1.y, h1.y), 0.f);
                float e6 = fmaxf(fmaf(bl(u.w), s1.z, h1.z), 0.f);
                float e7 = fmaxf(fmaf(bh(u.w), s1.w, h1.w), 0.f);
                r.x = (unsigned int)f2b(e0) | ((unsigned int)f2b(e1) << 16);
                r.y = (unsigned int)f2b(e2) | ((unsigned int)f2b(e3) << 16);
                r.z = (unsigned int)f2b(e4) | ((unsigned int)f2b(e5) << 16);
                r.w = (unsigned int)f2b(e6) | ((unsigned int)f2b(e7) << 16);
                a2[tt][ks] = *(bf16x8*)&r;
            }
        }
    }
    __syncthreads();

    f32x4 acc[2][NF];
#pragma unroll
    for (int tt = 0; tt < 2; ++tt)
#pragma unroll
        for (int nf = 0; nf < NF; ++nf) acc[tt][nf] = (f32x4){0.f, 0.f, 0.f, 0.f};

#pragma unroll
    for (int ks = 0; ks < 4; ++ks) {
#pragma unroll
        for (int nf = 0; nf < NF; ++nf) {
            bf16x8 wl = *(const bf16x8*)&wlds[((0 * NF + nf) * 4 + ks) * 64 + l];
            bf16x8 wr = *(const bf16x8*)&wlds[((1 * NF + nf) * 4 + ks) * 64 + l];
            acc[0][nf] = __builtin_amdgcn_mfma_f32_16x16x32_bf16(a1[0][ks], wl, acc[0][nf], 0, 0, 0);
            acc[1][nf] = __builtin_amdgcn_mfma_f32_16x16x32_bf16(a1[1][ks], wl, acc[1][nf], 0, 0, 0);
            acc[0][nf] = __builtin_amdgcn_mfma_f32_16x16x32_bf16(a2[0][ks], wr, acc[0][nf], 0, 0, 0);
            acc[1][nf] = __builtin_amdgcn_mfma_f32_16x16x32_bf16(a2[1][ks], wr, acc[1][nf], 0, 0, 0);
        }
    }

    // C/D layout: col = lane&15 (within frag), row = ko*4 + reg
#pragma unroll
    for (int tt = 0; tt < 2; ++tt) {
        int orow0 = rbase + tt * 16 + ko * 4;
#pragma unroll
        for (int nf = 0; nf < NF; ++nf) {
            int col = nf * 16 + lr;
            float bs = bias[col];
            float s = 0.f, q = 0.f;
#pragma unroll
            for (int j = 0; j < 4; ++j) {
                int r = orow0 + j;
                if (r < N_NODES) {
                    float v = acc[tt][nf][j] + bs;
                    if (BF16OUT) hout[(size_t)r * 128 + col] = f2b(v);
                    else         fout[(size_t)r * 64 + col] = v;
                    s += v;
                    q += v * v;
                }
            }
            if (STATS) {
                s += __shfl_xor(s, 16);
                s += __shfl_xor(s, 32);
                q += __shfl_xor(q, 16);
                q += __shfl_xor(q, 32);
                if (ko == 0) {
                    atomicAdd(&colsum[col], s);
                    atomicAdd(&colsq[col], q);
                }
            }
        }
    }
    if (STATS) {
        __syncthreads();
        if (t < O) {
            atomicAdd(&cs[t], colsum[t]);
            atomicAdd(&cq[t], colsq[t]);
        }
    }
}

__global__ void bn_prep(const float* __restrict__ cs, const float* __restrict__ cq,
                        const float* __restrict__ g, const float* __restrict__ be,
                        float* __restrict__ scale, float* __restrict__ shift) {
    int f = threadIdx.x;
    float mu = cs[f] * (1.0f / N_NODES);
    float var = cq[f] * (1.0f / N_NODES) - mu * mu;
    float sc = g[f] * rsqrtf(var + BN_EPS);
    scale[f] = sc;
    shift[f] = be[f] - mu * sc;
}

// ---------------------------------------------------------------------------
extern "C" void kernel_launch(void* const* d_in, const int* in_sizes, int n_in,
                              void* d_out, int out_size, void* d_ws, size_t ws_size,
                              hipStream_t stream) {
    const float* x   = (const float*)d_in[0];
    const int*   ei  = (const int*)d_in[1];
    const float* Wl1 = (const float*)d_in[2];
    const float* Wr1 = (const float*)d_in[3];
    const float* b1  = (const float*)d_in[4];
    const float* g1  = (const float*)d_in[5];
    const float* be1 = (const float*)d_in[6];
    const float* Wl2 = (const float*)d_in[7];
    const float* Wr2 = (const float*)d_in[8];
    const float* b2  = (const float*)d_in[9];
    const float* g2  = (const float*)d_in[10];
    const float* be2 = (const float*)d_in[11];
    const float* Wl3 = (const float*)d_in[12];
    const float* Wr3 = (const float*)d_in[13];
    const float* b3  = (const float*)d_in[14];
    float* out = (float*)d_out;

    char* p = (char*)d_ws;
    size_t off = 0;
    auto alloc = [&](size_t bytes) {
        char* r = p + off;
        off = (off + bytes + 255) & ~(size_t)255;
        return r;
    };
    int*            gcur  = (int*)alloc((size_t)NB * 4);
    int*            bbase = (int*)alloc((size_t)NB * 4);
    unsigned int*   bdata = (unsigned int*)alloc((size_t)NB * BCAP * 4);
    int*            row   = (int*)alloc((size_t)(N_NODES + 1) * 4);
    int*            csrc  = (int*)alloc((size_t)N_EDGES * 4);
    unsigned short* xb    = (unsigned short*)alloc((size_t)N_NODES * 128 * 2);
    unsigned short* mn    = (unsigned short*)alloc((size_t)N_NODES * 128 * 2);
    unsigned short* h1    = (unsigned short*)alloc((size_t)N_NODES * 128 * 2);
    unsigned short* h2    = (unsigned short*)alloc((size_t)N_NODES * 128 * 2);
    unsigned short* wbf   = (unsigned short*)alloc((size_t)81920 * 2);
    float*          cs    = (float*)alloc(256 * 4);   // cs[128] | cq[128]
    float*          cq    = cs + 128;
    float*          scl1  = (float*)alloc(128 * 4);
    float*          shf1  = (float*)alloc(128 * 4);
    float*          scl2  = (float*)alloc(128 * 4);
    float*          shf2  = (float*)alloc(128 * 4);
    (void)ws_size; (void)n_in; (void)in_sizes; (void)out_size;

    unsigned short* wl1b = wbf;
    unsigned short* wr1b = wbf + 16384;
    unsigned short* wl2b = wbf + 32768;
    unsigned short* wr2b = wbf + 49152;
    unsigned short* wl3b = wbf + 65536;
    unsigned short* wr3b = wbf + 73728;

    const int NBLK8 = (N_NODES + 7) / 8;            // 6250
    const int GBLK  = (N_NODES + 127) / 128;        // 391
    const int CBLK  = (N_NODES * 32 + 255) / 256;   // 6250

    // casts + CSR build (dense-write bucket sort)
    cast_x<<<CBLK, 256, 0, stream>>>(x, xb);
    wcast<<<320, 256, 0, stream>>>(Wl1, Wr1, Wl2, Wr2, Wl3, Wr3, wbf);
    init_gcur<<<1, 256, 0, stream>>>(gcur);
    bucket_scatter<<<SCAT_BLOCKS, 256, 0, stream>>>(ei, gcur, bdata);
    scan_buckets<<<1, 256, 0, stream>>>(gcur, bbase, row);
    bucket_fill<<<NB, 256, 0, stream>>>(bdata, gcur, bbase, row, csrc);

    // Layer 1
    agg_mean_bf16<false><<<NBLK8, 256, 0, stream>>>(xb, row, csrc, nullptr, nullptr, mn);
    hipMemsetAsync(cs, 0, 256 * 4, stream);
    gemm_mfma<128, true, true, false><<<GBLK, 256, 0, stream>>>(
        mn, xb, wl1b, wr1b, b1, nullptr, nullptr, h1, nullptr, cs, cq);
    bn_prep<<<1, 128, 0, stream>>>(cs, cq, g1, be1, scl1, shf1);

    // Layer 2 (h1 raw; BN1+ReLU folded into consumers)
    agg_mean_bf16<true><<<NBLK8, 256, 0, stream>>>(h1, row, csrc, scl1, shf1, mn);
    hipMemsetAsync(cs, 0, 256 * 4, stream);
    gemm_mfma<128, true, true, true><<<GBLK, 256, 0, stream>>>(
        mn, h1, wl2b, wr2b, b2, scl1, shf1, h2, nullptr, cs, cq);
    bn_prep<<<1, 128, 0, stream>>>(cs, cq, g2, be2, scl2, shf2);

    // Layer 3 (h2 raw; BN2+ReLU folded into consumers) -> f32 d_out
    agg_mean_bf16<true><<<NBLK8, 256, 0, stream>>>(h2, row, csrc, scl2, shf2, mn);
    gemm_mfma<64, false, false, true><<<GBLK, 256, 0, stream>>>(
        mn, h2, wl3b, wr3b, b3, scl2, shf2, nullptr, out, nullptr, nullptr);
}